// Round 1
// baseline (678.337 us; speedup 1.0000x reference)
//
#include <hip/hip_runtime.h>

#define HD 128
#define NEG 0.2f
#define BNEPS 1e-5f

// ---------------- CSR build ----------------

__global__ void k_init_deg(int* __restrict__ deg, int n) {
  int i = blockIdx.x * blockDim.x + threadIdx.x;
  if (i < n) deg[i] = 1;  // self-loop
}

__global__ void k_hist(const int* __restrict__ dst, int* __restrict__ deg, int E) {
  int i = blockIdx.x * blockDim.x + threadIdx.x;
  if (i < E) atomicAdd(&deg[dst[i]], 1);
}

// single-block inclusive scan -> exclusive offsets
__global__ __launch_bounds__(1024) void k_scan(const int* __restrict__ deg,
                                               int* __restrict__ offs, int n) {
  __shared__ int sd[1024];
  __shared__ int carry;
  int tid = threadIdx.x;
  if (tid == 0) carry = 0;
  __syncthreads();
  for (int base = 0; base < n; base += 1024) {
    int i = base + tid;
    int v = (i < n) ? deg[i] : 0;
    sd[tid] = v;
    __syncthreads();
    for (int off = 1; off < 1024; off <<= 1) {
      int t = (tid >= off) ? sd[tid - off] : 0;
      __syncthreads();
      sd[tid] += t;
      __syncthreads();
    }
    int inc = sd[tid] + carry;
    if (i < n) offs[i + 1] = inc;
    __syncthreads();
    if (tid == 1023) carry = inc;
    __syncthreads();
  }
  if (tid == 0) offs[0] = 0;
}

__global__ void k_fill_self(const int* __restrict__ offs, int* __restrict__ csr,
                            int* __restrict__ cursor, int n) {
  int i = blockIdx.x * blockDim.x + threadIdx.x;
  if (i < n) { int o = offs[i]; csr[o] = i; cursor[i] = o + 1; }
}

__global__ void k_fill_edges(const int* __restrict__ src, const int* __restrict__ dst,
                             int* __restrict__ cursor, int* __restrict__ csr, int E) {
  int i = blockIdx.x * blockDim.x + threadIdx.x;
  if (i < E) { int p = atomicAdd(&cursor[dst[i]], 1); csr[p] = src[i]; }
}

// ---------------- GEMM + score epilogue ----------------
// h = X @ W  (N x K) @ (K x 128); also s_src = h @ a_s, s_dst = h @ a_d.
// Block = 256 thr (4 waves). W staged in LDS. Each wave: 4 iterations of a
// 4-row group; lane covers cols (2*lane, 2*lane+1). x loads are wave-uniform
// (scalar path).
template <int K>
__global__ __launch_bounds__(256)
void k_gemm(const float* __restrict__ X, const float* __restrict__ W,
            const float* __restrict__ a_s, const float* __restrict__ a_d,
            float* __restrict__ Hh, float* __restrict__ ssrc,
            float* __restrict__ sdst, int n) {
  __shared__ float Wl[K * HD];
  for (int i = threadIdx.x; i < K * HD; i += 256) Wl[i] = W[i];
  __syncthreads();
  const int wave = threadIdx.x >> 6, lane = threadIdx.x & 63;
  const int c0 = lane * 2;
  const float2 as2 = *(const float2*)&a_s[c0];
  const float2 ad2 = *(const float2*)&a_d[c0];
  const int base = blockIdx.x * 64 + wave * 16;
  for (int it = 0; it < 4; ++it) {
    const int r0 = base + it * 4;
    if (r0 >= n) return;
    const float* xp0 = X + (long)((r0 + 0 < n) ? r0 + 0 : n - 1) * K;
    const float* xp1 = X + (long)((r0 + 1 < n) ? r0 + 1 : n - 1) * K;
    const float* xp2 = X + (long)((r0 + 2 < n) ? r0 + 2 : n - 1) * K;
    const float* xp3 = X + (long)((r0 + 3 < n) ? r0 + 3 : n - 1) * K;
    float a00 = 0.f, a01 = 0.f, a10 = 0.f, a11 = 0.f;
    float a20 = 0.f, a21 = 0.f, a30 = 0.f, a31 = 0.f;
#pragma unroll 4
    for (int k = 0; k < K; ++k) {
      float2 w2 = *(const float2*)&Wl[k * HD + c0];
      float x0 = xp0[k], x1 = xp1[k], x2 = xp2[k], x3 = xp3[k];
      a00 = fmaf(x0, w2.x, a00); a01 = fmaf(x0, w2.y, a01);
      a10 = fmaf(x1, w2.x, a10); a11 = fmaf(x1, w2.y, a11);
      a20 = fmaf(x2, w2.x, a20); a21 = fmaf(x2, w2.y, a21);
      a30 = fmaf(x3, w2.x, a30); a31 = fmaf(x3, w2.y, a31);
    }
    float acc[4][2] = {{a00, a01}, {a10, a11}, {a20, a21}, {a30, a31}};
#pragma unroll
    for (int i = 0; i < 4; ++i) {
      int r = r0 + i;
      if (r >= n) break;  // r uniform across wave
      float ps = acc[i][0] * as2.x + acc[i][1] * as2.y;
      float pd = acc[i][0] * ad2.x + acc[i][1] * ad2.y;
#pragma unroll
      for (int off = 32; off; off >>= 1) {
        ps += __shfl_xor(ps, off, 64);
        pd += __shfl_xor(pd, off, 64);
      }
      if (lane == 0) { ssrc[r] = ps; sdst[r] = pd; }
      *(float2*)&Hh[(long)r * HD + c0] = make_float2(acc[i][0], acc[i][1]);
    }
  }
}

// ---------------- per-dst-node softmax aggregation ----------------
// One wave per destination node. Fused: +bias, BatchNorm(inference), ReLU.
__global__ __launch_bounds__(256)
void k_agg(const float* __restrict__ Hh, const float* __restrict__ ssrc,
           const float* __restrict__ sdst, const int* __restrict__ offs,
           const int* __restrict__ csr, const float* __restrict__ bias,
           const float* __restrict__ gam, const float* __restrict__ bet,
           const float* __restrict__ mu, const float* __restrict__ var,
           float* __restrict__ Y, int n) {
  const int wid = (blockIdx.x * blockDim.x + threadIdx.x) >> 6;
  const int lane = threadIdx.x & 63;
  if (wid >= n) return;
  const int s0 = offs[wid], s1 = offs[wid + 1];
  const float sdv = sdst[wid];
  // pass 1: segment max (wave-parallel)
  float mx = -1e30f;
  for (int j = s0 + lane; j < s1; j += 64) {
    int s = csr[j];
    float e = ssrc[s] + sdv;
    e = (e > 0.f) ? e : NEG * e;
    mx = fmaxf(mx, e);
  }
#pragma unroll
  for (int off = 32; off; off >>= 1) mx = fmaxf(mx, __shfl_xor(mx, off, 64));
  // pass 2: exp-sum + weighted accumulation (uniform loop; h gather per-lane)
  const int c0 = lane * 2;
  float denom = 0.f, acc0 = 0.f, acc1 = 0.f;
  for (int j = s0; j < s1; ++j) {
    int s = csr[j];
    float e = ssrc[s] + sdv;
    e = (e > 0.f) ? e : NEG * e;
    float ex = __expf(e - mx);
    denom += ex;
    float2 hv = *(const float2*)&Hh[(long)s * HD + c0];
    acc0 = fmaf(ex, hv.x, acc0);
    acc1 = fmaf(ex, hv.y, acc1);
  }
  const float inv = 1.f / denom;
  float v0 = acc0 * inv + bias[c0];
  float v1 = acc1 * inv + bias[c0 + 1];
  float sc0 = gam[c0] * rsqrtf(var[c0] + BNEPS);
  float sc1 = gam[c0 + 1] * rsqrtf(var[c0 + 1] + BNEPS);
  v0 = fmaxf((v0 - mu[c0]) * sc0 + bet[c0], 0.f);
  v1 = fmaxf((v1 - mu[c0 + 1]) * sc1 + bet[c0 + 1], 0.f);
  *(float2*)&Y[(long)wid * HD + c0] = make_float2(v0, v1);
}

// ---------------- global mean pool + MLP head ----------------
// batch is sorted: one wave per graph; binary-search segment, register mean,
// fused head: out[g] = relu(pooled@lw1+lb1) @ lw2 + lb2.
__global__ __launch_bounds__(64)
void k_pool_head(const float* __restrict__ Y, const int* __restrict__ batch, int n,
                 const float* __restrict__ lw1, const float* __restrict__ lb1,
                 const float* __restrict__ lw2, const float* __restrict__ lb2,
                 float* __restrict__ out) {
  const int g = blockIdx.x;
  const int lane = threadIdx.x;
  int lo = 0, hi = n;
  while (lo < hi) { int mid = (lo + hi) >> 1; if (batch[mid] < g) lo = mid + 1; else hi = mid; }
  const int start = lo;
  hi = n;
  while (lo < hi) { int mid = (lo + hi) >> 1; if (batch[mid] < g + 1) lo = mid + 1; else hi = mid; }
  const int end = lo;
  const int c0 = lane * 2;
  float m0 = 0.f, m1 = 0.f;
  for (int i = start; i < end; ++i) {
    float2 hv = *(const float2*)&Y[(long)i * HD + c0];
    m0 += hv.x;
    m1 += hv.y;
  }
  const float cnt = (float)(end - start);
  const float invc = (cnt > 0.f) ? 1.f / cnt : 0.f;
  m0 *= invc;
  m1 *= invc;
  float t0 = lb1[c0], t1 = lb1[c0 + 1];
  for (int k = 0; k < HD; ++k) {
    float pv = __shfl((k & 1) ? m1 : m0, k >> 1, 64);
    float2 w2 = *(const float2*)&lw1[k * HD + c0];
    t0 = fmaf(pv, w2.x, t0);
    t1 = fmaf(pv, w2.y, t1);
  }
  t0 = fmaxf(t0, 0.f);
  t1 = fmaxf(t1, 0.f);
  float p = t0 * lw2[c0] + t1 * lw2[c0 + 1];
#pragma unroll
  for (int off = 32; off; off >>= 1) p += __shfl_xor(p, off, 64);
  if (lane == 0) out[g] = p + lb2[0];
}

// ---------------- launch ----------------

extern "C" void kernel_launch(void* const* d_in, const int* in_sizes, int n_in,
                              void* d_out, int out_size, void* d_ws, size_t ws_size,
                              hipStream_t stream) {
  const float* x = (const float*)d_in[0];
  const int* ei = (const int*)d_in[1];
  const int* batch = (const int*)d_in[2];
  const float* W1 = (const float*)d_in[3];
  const float* as1 = (const float*)d_in[4];
  const float* ad1 = (const float*)d_in[5];
  const float* b1 = (const float*)d_in[6];
  const float* W2 = (const float*)d_in[7];
  const float* as2 = (const float*)d_in[8];
  const float* ad2 = (const float*)d_in[9];
  const float* b2 = (const float*)d_in[10];
  const float* W3 = (const float*)d_in[11];
  const float* as3 = (const float*)d_in[12];
  const float* ad3 = (const float*)d_in[13];
  const float* b3 = (const float*)d_in[14];
  const float* g1 = (const float*)d_in[15];
  const float* be1 = (const float*)d_in[16];
  const float* m1 = (const float*)d_in[17];
  const float* v1 = (const float*)d_in[18];
  const float* g2 = (const float*)d_in[19];
  const float* be2 = (const float*)d_in[20];
  const float* m2 = (const float*)d_in[21];
  const float* v2 = (const float*)d_in[22];
  const float* g3 = (const float*)d_in[23];
  const float* be3 = (const float*)d_in[24];
  const float* m3 = (const float*)d_in[25];
  const float* v3 = (const float*)d_in[26];
  const float* lw1 = (const float*)d_in[27];
  const float* lb1 = (const float*)d_in[28];
  const float* lw2 = (const float*)d_in[29];
  const float* lb2 = (const float*)d_in[30];

  const int n = in_sizes[0] / 64;   // 50000
  const int E = in_sizes[1] / 2;    // 640000
  const int* src = ei;
  const int* dst = ei + E;

  // workspace carve (floats/ints, 4B each)
  float* hbuf = (float*)d_ws;                 // n*128
  float* ybuf = hbuf + (long)n * HD;          // n*128
  float* ssrc = ybuf + (long)n * HD;          // n
  float* sdstv = ssrc + n;                    // n
  int* deg = (int*)(sdstv + n);               // n
  int* offs = deg + n;                        // n+1
  int* cursor = offs + n + 1;                 // n
  int* csr = cursor + n;                      // E+n

  const int B = 256;
  dim3 blk(B);

  // CSR build (reused by all 3 layers)
  k_init_deg<<<dim3((n + B - 1) / B), blk, 0, stream>>>(deg, n);
  k_hist<<<dim3((E + B - 1) / B), blk, 0, stream>>>(dst, deg, E);
  k_scan<<<dim3(1), dim3(1024), 0, stream>>>(deg, offs, n);
  k_fill_self<<<dim3((n + B - 1) / B), blk, 0, stream>>>(offs, csr, cursor, n);
  k_fill_edges<<<dim3((E + B - 1) / B), blk, 0, stream>>>(src, dst, cursor, csr, E);

  const dim3 ggrid((n + 63) / 64);
  const dim3 agrid((n + 3) / 4);

  // layer 1
  k_gemm<64><<<ggrid, blk, 0, stream>>>(x, W1, as1, ad1, hbuf, ssrc, sdstv, n);
  k_agg<<<agrid, blk, 0, stream>>>(hbuf, ssrc, sdstv, offs, csr, b1, g1, be1, m1, v1, ybuf, n);
  // layer 2
  k_gemm<128><<<ggrid, blk, 0, stream>>>(ybuf, W2, as2, ad2, hbuf, ssrc, sdstv, n);
  k_agg<<<agrid, blk, 0, stream>>>(hbuf, ssrc, sdstv, offs, csr, b2, g2, be2, m2, v2, ybuf, n);
  // layer 3
  k_gemm<128><<<ggrid, blk, 0, stream>>>(ybuf, W3, as3, ad3, hbuf, ssrc, sdstv, n);
  k_agg<<<agrid, blk, 0, stream>>>(hbuf, ssrc, sdstv, offs, csr, b3, g3, be3, m3, v3, ybuf, n);

  // pool + head
  k_pool_head<<<dim3(256), dim3(64), 0, stream>>>(ybuf, batch, n, lw1, lb1, lw2, lb2,
                                                  (float*)d_out);
}

// Round 2
// 401.378 us; speedup vs baseline: 1.6900x; 1.6900x over previous
//
#include <hip/hip_runtime.h>

#define HD 128
#define NEG 0.2f
#define BNEPS 1e-5f

typedef unsigned int uint32;

// ---------------- wave helpers ----------------

__device__ inline float wave_max_f(float v) {
#pragma unroll
  for (int off = 32; off; off >>= 1) v = fmaxf(v, __shfl_xor(v, off, 64));
  return v;
}
__device__ inline float wave_sum_f(float v) {
#pragma unroll
  for (int off = 32; off; off >>= 1) v += __shfl_xor(v, off, 64);
  return v;
}
__device__ inline int wave_sum_i(int v) {
#pragma unroll
  for (int off = 32; off; off >>= 1) v += __shfl_xor(v, off, 64);
  return v;
}
__device__ inline int wave_iscan_i(int v, int lane) {
#pragma unroll
  for (int off = 1; off < 64; off <<= 1) {
    int t = __shfl_up(v, off, 64);
    if (lane >= off) v += t;
  }
  return v;
}
__device__ inline uint32 f2bf(float f) {  // fp32 -> bf16 (RNE), low 16 bits
  uint32 u = __float_as_uint(f);
  return (u + 0x7fffu + ((u >> 16) & 1u)) >> 16;
}

// ---------------- CSR build ----------------

__global__ void k_init_deg(int* __restrict__ deg, int n) {
  int i = blockIdx.x * blockDim.x + threadIdx.x;
  if (i < n) deg[i] = 1;  // self-loop
}

__global__ void k_hist(const int* __restrict__ dst, int* __restrict__ deg, int E) {
  int i = blockIdx.x * blockDim.x + threadIdx.x;
  if (i < E) atomicAdd(&deg[dst[i]], 1);
}

// hierarchical exclusive scan: (1) per-256-block sums, (2) scan partials, (3) final
__global__ __launch_bounds__(256) void k_scan_part(const int* __restrict__ deg,
                                                   int* __restrict__ part, int n) {
  const int t = threadIdx.x, lane = t & 63, wave = t >> 6;
  const int i = blockIdx.x * 256 + t;
  int v = (i < n) ? deg[i] : 0;
  int wv = wave_sum_i(v);
  __shared__ int ws[4];
  if (lane == 0) ws[wave] = wv;
  __syncthreads();
  if (t == 0) part[blockIdx.x] = ws[0] + ws[1] + ws[2] + ws[3];
}

__global__ __launch_bounds__(256) void k_scan_part2(int* __restrict__ part, int nb) {
  const int t = threadIdx.x, lane = t & 63, wave = t >> 6;
  int v = (t < nb) ? part[t] : 0;
  int x = wave_iscan_i(v, lane);
  __shared__ int ws[4];
  if (lane == 63) ws[wave] = x;
  __syncthreads();
  int add = 0;
#pragma unroll
  for (int w = 0; w < 4; ++w)
    if (w < wave) add += ws[w];
  x += add;
  if (t < nb) part[t] = x;  // inclusive scan of block sums
}

__global__ __launch_bounds__(256) void k_scan_final(const int* __restrict__ deg,
                                                    const int* __restrict__ part,
                                                    int* __restrict__ offs, int n) {
  const int t = threadIdx.x, lane = t & 63, wave = t >> 6;
  const int b = blockIdx.x;
  const int i = b * 256 + t;
  int v = (i < n) ? deg[i] : 0;
  int x = wave_iscan_i(v, lane);
  __shared__ int ws[4];
  if (lane == 63) ws[wave] = x;
  __syncthreads();
  int add = (b > 0) ? part[b - 1] : 0;
#pragma unroll
  for (int w = 0; w < 4; ++w)
    if (w < wave) add += ws[w];
  x += add;
  if (i < n) offs[i + 1] = x;
  if (i == 0) offs[0] = 0;
}

__global__ void k_fill_self(const int* __restrict__ offs, int* __restrict__ csr,
                            int* __restrict__ cursor, int n) {
  int i = blockIdx.x * blockDim.x + threadIdx.x;
  if (i < n) { int o = offs[i]; csr[o] = i; cursor[i] = o + 1; }
}

__global__ void k_fill_edges(const int* __restrict__ src, const int* __restrict__ dst,
                             int* __restrict__ cursor, int* __restrict__ csr, int E) {
  int i = blockIdx.x * blockDim.x + threadIdx.x;
  if (i < E) { int p = atomicAdd(&cursor[dst[i]], 1); csr[p] = src[i]; }
}

// ---------------- GEMM + score epilogue ----------------
// h = X @ W; s_src = h @ a_s; s_dst = h @ a_d. Scores in fp32; h stored packed bf16x2.
template <int K>
__global__ __launch_bounds__(256)
void k_gemm(const float* __restrict__ X, const float* __restrict__ W,
            const float* __restrict__ a_s, const float* __restrict__ a_d,
            uint32* __restrict__ Hh, float* __restrict__ ssrc,
            float* __restrict__ sdst, int n) {
  __shared__ float Wl[K * HD];
  for (int i = threadIdx.x; i < K * HD; i += 256) Wl[i] = W[i];
  __syncthreads();
  const int wave = threadIdx.x >> 6, lane = threadIdx.x & 63;
  const int c0 = lane * 2;
  const float2 as2 = *(const float2*)&a_s[c0];
  const float2 ad2 = *(const float2*)&a_d[c0];
  const int base = blockIdx.x * 64 + wave * 16;
  for (int it = 0; it < 4; ++it) {
    const int r0 = base + it * 4;
    if (r0 >= n) return;
    const float4* xq0 = (const float4*)(X + (long)min(r0 + 0, n - 1) * K);
    const float4* xq1 = (const float4*)(X + (long)min(r0 + 1, n - 1) * K);
    const float4* xq2 = (const float4*)(X + (long)min(r0 + 2, n - 1) * K);
    const float4* xq3 = (const float4*)(X + (long)min(r0 + 3, n - 1) * K);
    float a00 = 0.f, a01 = 0.f, a10 = 0.f, a11 = 0.f;
    float a20 = 0.f, a21 = 0.f, a30 = 0.f, a31 = 0.f;
#pragma unroll 2
    for (int kq = 0; kq < K / 4; ++kq) {
      float4 x0 = xq0[kq], x1 = xq1[kq], x2 = xq2[kq], x3 = xq3[kq];
      const float* wrow = &Wl[kq * 4 * HD + c0];
#pragma unroll
      for (int u = 0; u < 4; ++u) {
        float2 w2 = *(const float2*)&wrow[u * HD];
        float e0 = ((const float*)&x0)[u], e1 = ((const float*)&x1)[u];
        float e2 = ((const float*)&x2)[u], e3 = ((const float*)&x3)[u];
        a00 = fmaf(e0, w2.x, a00); a01 = fmaf(e0, w2.y, a01);
        a10 = fmaf(e1, w2.x, a10); a11 = fmaf(e1, w2.y, a11);
        a20 = fmaf(e2, w2.x, a20); a21 = fmaf(e2, w2.y, a21);
        a30 = fmaf(e3, w2.x, a30); a31 = fmaf(e3, w2.y, a31);
      }
    }
    float acc[4][2] = {{a00, a01}, {a10, a11}, {a20, a21}, {a30, a31}};
#pragma unroll
    for (int i = 0; i < 4; ++i) {
      int r = r0 + i;
      if (r >= n) break;  // uniform
      float ps = acc[i][0] * as2.x + acc[i][1] * as2.y;
      float pd = acc[i][0] * ad2.x + acc[i][1] * ad2.y;
#pragma unroll
      for (int off = 32; off; off >>= 1) {
        ps += __shfl_xor(ps, off, 64);
        pd += __shfl_xor(pd, off, 64);
      }
      if (lane == 0) { ssrc[r] = ps; sdst[r] = pd; }
      Hh[r * 64 + lane] = f2bf(acc[i][0]) | (f2bf(acc[i][1]) << 16);
    }
  }
}

// ---------------- per-dst-node softmax aggregation ----------------
// One wave per dst node. Pass 1: lanes load edge idx+score in parallel (kept in
// registers). Pass 2: readlane-broadcast + 8-wide unrolled bf16 h-gather.
// Fused: +bias, BatchNorm(inference), ReLU.
__global__ __launch_bounds__(256)
void k_agg(const uint32* __restrict__ Hh, const float* __restrict__ ssrc,
           const float* __restrict__ sdst, const int* __restrict__ offs,
           const int* __restrict__ csr, const float* __restrict__ bias,
           const float* __restrict__ gam, const float* __restrict__ bet,
           const float* __restrict__ mu, const float* __restrict__ var,
           float* __restrict__ Y, int n) {
  const int wid = (blockIdx.x * blockDim.x + threadIdx.x) >> 6;
  const int lane = threadIdx.x & 63;
  if (wid >= n) return;
  const int s0 = offs[wid], s1 = offs[wid + 1];
  const float sdv = sdst[wid];
  const int c0 = lane * 2;
  float acc0 = 0.f, acc1 = 0.f, denom = 0.f, mx = -1e30f;
  for (int base = s0; base < s1; base += 64) {
    const int m = min(64, s1 - base);
    int sidx = 0;
    float e = -1e30f;
    if (lane < m) {
      sidx = csr[base + lane];
      float t = ssrc[sidx] + sdv;
      e = (t > 0.f) ? t : NEG * t;
    }
    const float cmx = wave_max_f(e);
    const float nmx = fmaxf(mx, cmx);
    if (nmx > mx) {  // first chunk: exp(-huge)=0, accs are 0 anyway
      const float sc = __expf(mx - nmx);
      acc0 *= sc; acc1 *= sc; denom *= sc;
      mx = nmx;
    }
    const float p = (lane < m) ? __expf(e - mx) : 0.f;
    denom += wave_sum_f(p);
    int jj = 0;
    for (; jj + 8 <= m; jj += 8) {
      const int i0 = __builtin_amdgcn_readlane(sidx, jj + 0);
      const int i1 = __builtin_amdgcn_readlane(sidx, jj + 1);
      const int i2 = __builtin_amdgcn_readlane(sidx, jj + 2);
      const int i3 = __builtin_amdgcn_readlane(sidx, jj + 3);
      const int i4 = __builtin_amdgcn_readlane(sidx, jj + 4);
      const int i5 = __builtin_amdgcn_readlane(sidx, jj + 5);
      const int i6 = __builtin_amdgcn_readlane(sidx, jj + 6);
      const int i7 = __builtin_amdgcn_readlane(sidx, jj + 7);
      const uint32 pu = __float_as_uint(p);
      const float w0 = __uint_as_float(__builtin_amdgcn_readlane(pu, jj + 0));
      const float w1 = __uint_as_float(__builtin_amdgcn_readlane(pu, jj + 1));
      const float w2 = __uint_as_float(__builtin_amdgcn_readlane(pu, jj + 2));
      const float w3 = __uint_as_float(__builtin_amdgcn_readlane(pu, jj + 3));
      const float w4 = __uint_as_float(__builtin_amdgcn_readlane(pu, jj + 4));
      const float w5 = __uint_as_float(__builtin_amdgcn_readlane(pu, jj + 5));
      const float w6 = __uint_as_float(__builtin_amdgcn_readlane(pu, jj + 6));
      const float w7 = __uint_as_float(__builtin_amdgcn_readlane(pu, jj + 7));
      const uint32 g0 = Hh[i0 * 64 + lane];
      const uint32 g1 = Hh[i1 * 64 + lane];
      const uint32 g2 = Hh[i2 * 64 + lane];
      const uint32 g3 = Hh[i3 * 64 + lane];
      const uint32 g4 = Hh[i4 * 64 + lane];
      const uint32 g5 = Hh[i5 * 64 + lane];
      const uint32 g6 = Hh[i6 * 64 + lane];
      const uint32 g7 = Hh[i7 * 64 + lane];
      acc0 = fmaf(w0, __uint_as_float(g0 << 16), acc0);
      acc1 = fmaf(w0, __uint_as_float(g0 & 0xffff0000u), acc1);
      acc0 = fmaf(w1, __uint_as_float(g1 << 16), acc0);
      acc1 = fmaf(w1, __uint_as_float(g1 & 0xffff0000u), acc1);
      acc0 = fmaf(w2, __uint_as_float(g2 << 16), acc0);
      acc1 = fmaf(w2, __uint_as_float(g2 & 0xffff0000u), acc1);
      acc0 = fmaf(w3, __uint_as_float(g3 << 16), acc0);
      acc1 = fmaf(w3, __uint_as_float(g3 & 0xffff0000u), acc1);
      acc0 = fmaf(w4, __uint_as_float(g4 << 16), acc0);
      acc1 = fmaf(w4, __uint_as_float(g4 & 0xffff0000u), acc1);
      acc0 = fmaf(w5, __uint_as_float(g5 << 16), acc0);
      acc1 = fmaf(w5, __uint_as_float(g5 & 0xffff0000u), acc1);
      acc0 = fmaf(w6, __uint_as_float(g6 << 16), acc0);
      acc1 = fmaf(w6, __uint_as_float(g6 & 0xffff0000u), acc1);
      acc0 = fmaf(w7, __uint_as_float(g7 << 16), acc0);
      acc1 = fmaf(w7, __uint_as_float(g7 & 0xffff0000u), acc1);
    }
    for (; jj < m; ++jj) {
      const int s = __builtin_amdgcn_readlane(sidx, jj);
      const float w =
          __uint_as_float(__builtin_amdgcn_readlane(__float_as_uint(p), jj));
      const uint32 gv = Hh[s * 64 + lane];
      acc0 = fmaf(w, __uint_as_float(gv << 16), acc0);
      acc1 = fmaf(w, __uint_as_float(gv & 0xffff0000u), acc1);
    }
  }
  const float inv = 1.f / denom;
  float v0 = acc0 * inv + bias[c0];
  float v1 = acc1 * inv + bias[c0 + 1];
  const float sc0 = gam[c0] * rsqrtf(var[c0] + BNEPS);
  const float sc1 = gam[c0 + 1] * rsqrtf(var[c0 + 1] + BNEPS);
  v0 = fmaxf((v0 - mu[c0]) * sc0 + bet[c0], 0.f);
  v1 = fmaxf((v1 - mu[c0 + 1]) * sc1 + bet[c0 + 1], 0.f);
  *(float2*)&Y[(long)wid * HD + c0] = make_float2(v0, v1);
}

// ---------------- global mean pool + MLP head ----------------
// One 256-thread block (4 waves) per graph; waves split the row range, LDS
// combine, wave 0 runs the fused MLP head.
__global__ __launch_bounds__(256)
void k_pool_head(const float* __restrict__ Y, const int* __restrict__ batch, int n,
                 const float* __restrict__ lw1, const float* __restrict__ lb1,
                 const float* __restrict__ lw2, const float* __restrict__ lb2,
                 float* __restrict__ out) {
  const int g = blockIdx.x;
  const int wave = threadIdx.x >> 6, lane = threadIdx.x & 63;
  int lo = 0, hi = n;
  while (lo < hi) { int mid = (lo + hi) >> 1; if (batch[mid] < g) lo = mid + 1; else hi = mid; }
  const int start = lo;
  hi = n;
  while (lo < hi) { int mid = (lo + hi) >> 1; if (batch[mid] < g + 1) lo = mid + 1; else hi = mid; }
  const int end = lo;
  const int c0 = lane * 2;
  float m0 = 0.f, m1 = 0.f;
  for (int i = start + wave; i < end; i += 4) {
    float2 hv = *(const float2*)&Y[(long)i * HD + c0];
    m0 += hv.x;
    m1 += hv.y;
  }
  __shared__ float red[4][HD];
  red[wave][c0] = m0;
  red[wave][c0 + 1] = m1;
  __syncthreads();
  if (wave == 0) {
    m0 = red[0][c0] + red[1][c0] + red[2][c0] + red[3][c0];
    m1 = red[0][c0 + 1] + red[1][c0 + 1] + red[2][c0 + 1] + red[3][c0 + 1];
    const float cnt = (float)(end - start);
    const float invc = (cnt > 0.f) ? 1.f / cnt : 0.f;
    m0 *= invc;
    m1 *= invc;
    float t0 = lb1[c0], t1 = lb1[c0 + 1];
    for (int k = 0; k < HD; ++k) {
      float pv = __shfl((k & 1) ? m1 : m0, k >> 1, 64);
      float2 w2 = *(const float2*)&lw1[k * HD + c0];
      t0 = fmaf(pv, w2.x, t0);
      t1 = fmaf(pv, w2.y, t1);
    }
    t0 = fmaxf(t0, 0.f);
    t1 = fmaxf(t1, 0.f);
    float p = t0 * lw2[c0] + t1 * lw2[c0 + 1];
#pragma unroll
    for (int off = 32; off; off >>= 1) p += __shfl_xor(p, off, 64);
    if (lane == 0) out[g] = p + lb2[0];
  }
}

// ---------------- launch ----------------

extern "C" void kernel_launch(void* const* d_in, const int* in_sizes, int n_in,
                              void* d_out, int out_size, void* d_ws, size_t ws_size,
                              hipStream_t stream) {
  const float* x = (const float*)d_in[0];
  const int* ei = (const int*)d_in[1];
  const int* batch = (const int*)d_in[2];
  const float* W1 = (const float*)d_in[3];
  const float* as1 = (const float*)d_in[4];
  const float* ad1 = (const float*)d_in[5];
  const float* b1 = (const float*)d_in[6];
  const float* W2 = (const float*)d_in[7];
  const float* as2 = (const float*)d_in[8];
  const float* ad2 = (const float*)d_in[9];
  const float* b2 = (const float*)d_in[10];
  const float* W3 = (const float*)d_in[11];
  const float* as3 = (const float*)d_in[12];
  const float* ad3 = (const float*)d_in[13];
  const float* b3 = (const float*)d_in[14];
  const float* g1 = (const float*)d_in[15];
  const float* be1 = (const float*)d_in[16];
  const float* m1 = (const float*)d_in[17];
  const float* v1 = (const float*)d_in[18];
  const float* g2 = (const float*)d_in[19];
  const float* be2 = (const float*)d_in[20];
  const float* m2 = (const float*)d_in[21];
  const float* v2 = (const float*)d_in[22];
  const float* g3 = (const float*)d_in[23];
  const float* be3 = (const float*)d_in[24];
  const float* m3 = (const float*)d_in[25];
  const float* v3 = (const float*)d_in[26];
  const float* lw1 = (const float*)d_in[27];
  const float* lb1 = (const float*)d_in[28];
  const float* lw2 = (const float*)d_in[29];
  const float* lb2 = (const float*)d_in[30];

  const int n = in_sizes[0] / 64;  // 50000
  const int E = in_sizes[1] / 2;   // 640000
  const int* src = ei;
  const int* dst = ei + E;

  // workspace carve (4B units)
  uint32* hbuf = (uint32*)d_ws;              // n*64   (bf16x2 packed h)
  float* ybuf = (float*)(hbuf + (long)n * 64);  // n*128
  float* ssrc = ybuf + (long)n * HD;         // n
  float* sdstv = ssrc + n;                   // n
  int* deg = (int*)(sdstv + n);              // n
  int* offs = deg + n;                       // n+1
  int* cursor = offs + n + 1;                // n
  int* csr = cursor + n;                     // E+n
  int* part = csr + (E + n);                 // <=256

  const int B = 256;
  dim3 blk(B);
  const int nb = (n + B - 1) / B;

  // CSR build (reused by all 3 layers)
  k_init_deg<<<dim3(nb), blk, 0, stream>>>(deg, n);
  k_hist<<<dim3((E + B - 1) / B), blk, 0, stream>>>(dst, deg, E);
  k_scan_part<<<dim3(nb), blk, 0, stream>>>(deg, part, n);
  k_scan_part2<<<dim3(1), blk, 0, stream>>>(part, nb);
  k_scan_final<<<dim3(nb), blk, 0, stream>>>(deg, part, offs, n);
  k_fill_self<<<dim3(nb), blk, 0, stream>>>(offs, csr, cursor, n);
  k_fill_edges<<<dim3((E + B - 1) / B), blk, 0, stream>>>(src, dst, cursor, csr, E);

  const dim3 ggrid((n + 63) / 64);
  const dim3 agrid((n + 3) / 4);

  // layer 1
  k_gemm<64><<<ggrid, blk, 0, stream>>>(x, W1, as1, ad1, hbuf, ssrc, sdstv, n);
  k_agg<<<agrid, blk, 0, stream>>>(hbuf, ssrc, sdstv, offs, csr, b1, g1, be1, m1, v1, ybuf, n);
  // layer 2
  k_gemm<128><<<ggrid, blk, 0, stream>>>(ybuf, W2, as2, ad2, hbuf, ssrc, sdstv, n);
  k_agg<<<agrid, blk, 0, stream>>>(hbuf, ssrc, sdstv, offs, csr, b2, g2, be2, m2, v2, ybuf, n);
  // layer 3
  k_gemm<128><<<ggrid, blk, 0, stream>>>(ybuf, W3, as3, ad3, hbuf, ssrc, sdstv, n);
  k_agg<<<agrid, blk, 0, stream>>>(hbuf, ssrc, sdstv, offs, csr, b3, g3, be3, m3, v3, ybuf, n);

  // pool + head
  k_pool_head<<<dim3(256), blk, 0, stream>>>(ybuf, batch, n, lw1, lb1, lw2, lb2,
                                             (float*)d_out);
}

// Round 3
// 268.122 us; speedup vs baseline: 2.5300x; 1.4970x over previous
//
#include <hip/hip_runtime.h>

#define HD 128
#define NEG 0.2f
#define BNEPS 1e-5f

typedef unsigned int uint32;
typedef __attribute__((ext_vector_type(8))) short short8;   // 8 bf16 (4 VGPRs)
typedef __attribute__((ext_vector_type(4))) float floatx4;  // MFMA acc

// ---------------- wave helpers ----------------

__device__ inline float wave_max_f(float v) {
#pragma unroll
  for (int off = 32; off; off >>= 1) v = fmaxf(v, __shfl_xor(v, off, 64));
  return v;
}
__device__ inline float wave_sum_f(float v) {
#pragma unroll
  for (int off = 32; off; off >>= 1) v += __shfl_xor(v, off, 64);
  return v;
}
__device__ inline int wave_sum_i(int v) {
#pragma unroll
  for (int off = 32; off; off >>= 1) v += __shfl_xor(v, off, 64);
  return v;
}
__device__ inline int wave_iscan_i(int v, int lane) {
#pragma unroll
  for (int off = 1; off < 64; off <<= 1) {
    int t = __shfl_up(v, off, 64);
    if (lane >= off) v += t;
  }
  return v;
}
__device__ inline uint32 f2bf(float f) {  // fp32 -> bf16 (RNE), low 16 bits
  uint32 u = __float_as_uint(f);
  return (u + 0x7fffu + ((u >> 16) & 1u)) >> 16;
}

// ---------------- CSR build ----------------

__global__ void k_init_deg(int* __restrict__ deg, int n) {
  int i = blockIdx.x * blockDim.x + threadIdx.x;
  if (i < n) deg[i] = 1;  // self-loop
}

__global__ void k_hist(const int* __restrict__ dst, int* __restrict__ deg, int E) {
  int i = blockIdx.x * blockDim.x + threadIdx.x;
  if (i < E) atomicAdd(&deg[dst[i]], 1);
}

__global__ __launch_bounds__(256) void k_scan_part(const int* __restrict__ deg,
                                                   int* __restrict__ part, int n) {
  const int t = threadIdx.x, lane = t & 63, wave = t >> 6;
  const int i = blockIdx.x * 256 + t;
  int v = (i < n) ? deg[i] : 0;
  int wv = wave_sum_i(v);
  __shared__ int ws[4];
  if (lane == 0) ws[wave] = wv;
  __syncthreads();
  if (t == 0) part[blockIdx.x] = ws[0] + ws[1] + ws[2] + ws[3];
}

__global__ __launch_bounds__(256) void k_scan_part2(int* __restrict__ part, int nb) {
  const int t = threadIdx.x, lane = t & 63, wave = t >> 6;
  int v = (t < nb) ? part[t] : 0;
  int x = wave_iscan_i(v, lane);
  __shared__ int ws[4];
  if (lane == 63) ws[wave] = x;
  __syncthreads();
  int add = 0;
#pragma unroll
  for (int w = 0; w < 4; ++w)
    if (w < wave) add += ws[w];
  x += add;
  if (t < nb) part[t] = x;  // inclusive scan of block sums
}

__global__ __launch_bounds__(256) void k_scan_final(const int* __restrict__ deg,
                                                    const int* __restrict__ part,
                                                    int* __restrict__ offs, int n) {
  const int t = threadIdx.x, lane = t & 63, wave = t >> 6;
  const int b = blockIdx.x;
  const int i = b * 256 + t;
  int v = (i < n) ? deg[i] : 0;
  int x = wave_iscan_i(v, lane);
  __shared__ int ws[4];
  if (lane == 63) ws[wave] = x;
  __syncthreads();
  int add = (b > 0) ? part[b - 1] : 0;
#pragma unroll
  for (int w = 0; w < 4; ++w)
    if (w < wave) add += ws[w];
  x += add;
  if (i < n) offs[i + 1] = x;
  if (i == 0) offs[0] = 0;
}

__global__ void k_fill_self(const int* __restrict__ offs, int* __restrict__ csr,
                            int* __restrict__ cursor, int n) {
  int i = blockIdx.x * blockDim.x + threadIdx.x;
  if (i < n) { int o = offs[i]; csr[o] = i; cursor[i] = o + 1; }
}

__global__ void k_fill_edges(const int* __restrict__ src, const int* __restrict__ dst,
                             int* __restrict__ cursor, int* __restrict__ csr, int E) {
  int i = blockIdx.x * blockDim.x + threadIdx.x;
  if (i < E) { int p = atomicAdd(&cursor[dst[i]], 1); csr[p] = src[i]; }
}

// ---------------- W pre-pack: fp32 [K][128] -> bf16 fragment-major ----------------
// PW slot ((ct*(K/32)+kc)*64 + lane)*8 + e  =  bf16(W[kc*32+(lane>>4)*8+e][ct*16+(lane&15)])
template <int K>
__global__ __launch_bounds__(256) void k_packw(const float* __restrict__ W,
                                               uint32* __restrict__ PW) {
  const int idx = blockIdx.x * 256 + threadIdx.x;  // one uint32 (2 bf16)
  const int total = 8 * (K / 32) * 64 * 4;
  if (idx >= total) return;
  const int e2 = idx & 3;
  const int l = (idx >> 2) & 63;
  const int f = idx >> 8;
  const int kc = f % (K / 32), ct = f / (K / 32);
  const int k0 = kc * 32 + (l >> 4) * 8 + e2 * 2;
  const int col = ct * 16 + (l & 15);
  const float w0 = W[k0 * HD + col], w1 = W[(k0 + 1) * HD + col];
  PW[idx] = f2bf(w0) | (f2bf(w1) << 16);
}

// ---------------- MFMA GEMM + score epilogue ----------------
// h = X @ W via mfma_f32_16x16x32_bf16. Block = 64 rows, 4 waves split 128 cols
// (wave w: cols [32w,32w+32)). B panel held in registers; X tile staged to LDS
// (bf16, XOR-swizzled). Hh written packed bf16x2 in slot layout:
//   Hh[r*64 + w*16 + (l&15)] = pack(col w*32+(l&15), col w*32+16+(l&15))
// Scores s_src/s_dst reduced in-wave (16-lane xor-shuffle) + LDS cross-wave.
template <int K>
__global__ __launch_bounds__(256)
void k_gemm_mfma(const float* __restrict__ X, const uint32* __restrict__ PW,
                 const float* __restrict__ a_s, const float* __restrict__ a_d,
                 uint32* __restrict__ Hh, float* __restrict__ ssrc,
                 float* __restrict__ sdst, int n) {
  constexpr int KC = K / 32;
  __shared__ uint32 Xl[64 * K / 2];
  __shared__ float sred[4][64][2];
  const int t = threadIdx.x;
  const int wv = t >> 6, l = t & 63;
  const int rowbase = blockIdx.x * 64;

  // B fragments -> registers (global, before barrier; overlaps LDS staging)
  short8 bfr[2][KC];
#pragma unroll
  for (int c2 = 0; c2 < 2; ++c2)
#pragma unroll
    for (int kc = 0; kc < KC; ++kc) {
      const int f = (wv * 2 + c2) * KC + kc;
      bfr[c2][kc] = *((const short8*)PW + f * 64 + l);
    }

  // stage X -> LDS bf16 swizzled
  {
    const int PAIRS = 64 * K / 2;
    for (int i = t; i < PAIRS; i += 256) {
      const int row = i / (K / 2), kp = i % (K / 2);
      const int r = min(rowbase + row, n - 1);
      const float2 v = *(const float2*)&X[(long)r * K + kp * 2];
      const uint32 p = f2bf(v.x) | (f2bf(v.y) << 16);
      int byte = row * (K * 2) + kp * 4;
      byte ^= (row & 7) << 4;
      Xl[byte >> 2] = p;
    }
  }
  __syncthreads();

  floatx4 acc[4][2];
#pragma unroll
  for (int rt = 0; rt < 4; ++rt) {
    acc[rt][0] = (floatx4){0.f, 0.f, 0.f, 0.f};
    acc[rt][1] = (floatx4){0.f, 0.f, 0.f, 0.f};
  }
  const int row_l = l & 15, kgrp = l >> 4;
#pragma unroll
  for (int rt = 0; rt < 4; ++rt) {
    const int row = rt * 16 + row_l;
#pragma unroll
    for (int kc = 0; kc < KC; ++kc) {
      const int byte = (row * (K * 2) + kc * 64 + kgrp * 16) ^ ((row & 7) << 4);
      const short8 af = *(const short8*)((const char*)Xl + byte);
      acc[rt][0] = __builtin_amdgcn_mfma_f32_16x16x32_bf16(af, bfr[0][kc], acc[rt][0], 0, 0, 0);
      acc[rt][1] = __builtin_amdgcn_mfma_f32_16x16x32_bf16(af, bfr[1][kc], acc[rt][1], 0, 0, 0);
    }
  }

  // epilogue: scores + packed bf16 store
  const int j0 = wv * 32 + (l & 15);
  const float as0 = a_s[j0], as1 = a_s[j0 + 16];
  const float ad0 = a_d[j0], ad1 = a_d[j0 + 16];
#pragma unroll
  for (int rt = 0; rt < 4; ++rt) {
#pragma unroll
    for (int r = 0; r < 4; ++r) {
      const float v0 = acc[rt][0][r], v1 = acc[rt][1][r];
      float ps = v0 * as0 + v1 * as1;
      float pd = v0 * ad0 + v1 * ad1;
#pragma unroll
      for (int m = 1; m < 16; m <<= 1) {
        ps += __shfl_xor(ps, m, 64);
        pd += __shfl_xor(pd, m, 64);
      }
      const int rowl = rt * 16 + (l >> 4) * 4 + r;
      if ((l & 15) == 0) {
        sred[wv][rowl][0] = ps;
        sred[wv][rowl][1] = pd;
      }
      const int R = rowbase + rowl;
      if (R < n) Hh[(long)R * 64 + wv * 16 + (l & 15)] = f2bf(v0) | (f2bf(v1) << 16);
    }
  }
  __syncthreads();
  if (t < 64) {
    const int R = rowbase + t;
    if (R < n) {
      ssrc[R] = sred[0][t][0] + sred[1][t][0] + sred[2][t][0] + sred[3][t][0];
      sdst[R] = sred[0][t][1] + sred[1][t][1] + sred[2][t][1] + sred[3][t][1];
    }
  }
}

// ---------------- per-dst-node softmax aggregation ----------------
// One wave per dst node; slot-layout columns: c0=(lane>>4)*32+(lane&15), c1=c0+16.
__global__ __launch_bounds__(256)
void k_agg(const uint32* __restrict__ Hh, const float* __restrict__ ssrc,
           const float* __restrict__ sdst, const int* __restrict__ offs,
           const int* __restrict__ csr, const float* __restrict__ bias,
           const float* __restrict__ gam, const float* __restrict__ bet,
           const float* __restrict__ mu, const float* __restrict__ var,
           float* __restrict__ Y, int n) {
  const int wid = (blockIdx.x * blockDim.x + threadIdx.x) >> 6;
  const int lane = threadIdx.x & 63;
  if (wid >= n) return;
  const int s0 = offs[wid], s1 = offs[wid + 1];
  const float sdv = sdst[wid];
  const int c0 = (lane >> 4) * 32 + (lane & 15);
  const int c1 = c0 + 16;
  float acc0 = 0.f, acc1 = 0.f, denom = 0.f, mx = -1e30f;
  for (int base = s0; base < s1; base += 64) {
    const int m = min(64, s1 - base);
    int sidx = 0;
    float e = -1e30f;
    if (lane < m) {
      sidx = csr[base + lane];
      float tt = ssrc[sidx] + sdv;
      e = (tt > 0.f) ? tt : NEG * tt;
    }
    const float cmx = wave_max_f(e);
    const float nmx = fmaxf(mx, cmx);
    if (nmx > mx) {
      const float sc = __expf(mx - nmx);
      acc0 *= sc; acc1 *= sc; denom *= sc;
      mx = nmx;
    }
    const float p = (lane < m) ? __expf(e - mx) : 0.f;
    denom += wave_sum_f(p);
    int jj = 0;
    for (; jj + 8 <= m; jj += 8) {
      const int i0 = __builtin_amdgcn_readlane(sidx, jj + 0);
      const int i1 = __builtin_amdgcn_readlane(sidx, jj + 1);
      const int i2 = __builtin_amdgcn_readlane(sidx, jj + 2);
      const int i3 = __builtin_amdgcn_readlane(sidx, jj + 3);
      const int i4 = __builtin_amdgcn_readlane(sidx, jj + 4);
      const int i5 = __builtin_amdgcn_readlane(sidx, jj + 5);
      const int i6 = __builtin_amdgcn_readlane(sidx, jj + 6);
      const int i7 = __builtin_amdgcn_readlane(sidx, jj + 7);
      const uint32 pu = __float_as_uint(p);
      const float w0 = __uint_as_float(__builtin_amdgcn_readlane(pu, jj + 0));
      const float w1 = __uint_as_float(__builtin_amdgcn_readlane(pu, jj + 1));
      const float w2 = __uint_as_float(__builtin_amdgcn_readlane(pu, jj + 2));
      const float w3 = __uint_as_float(__builtin_amdgcn_readlane(pu, jj + 3));
      const float w4 = __uint_as_float(__builtin_amdgcn_readlane(pu, jj + 4));
      const float w5 = __uint_as_float(__builtin_amdgcn_readlane(pu, jj + 5));
      const float w6 = __uint_as_float(__builtin_amdgcn_readlane(pu, jj + 6));
      const float w7 = __uint_as_float(__builtin_amdgcn_readlane(pu, jj + 7));
      const uint32 g0 = Hh[i0 * 64 + lane];
      const uint32 g1 = Hh[i1 * 64 + lane];
      const uint32 g2 = Hh[i2 * 64 + lane];
      const uint32 g3 = Hh[i3 * 64 + lane];
      const uint32 g4 = Hh[i4 * 64 + lane];
      const uint32 g5 = Hh[i5 * 64 + lane];
      const uint32 g6 = Hh[i6 * 64 + lane];
      const uint32 g7 = Hh[i7 * 64 + lane];
      acc0 = fmaf(w0, __uint_as_float(g0 << 16), acc0);
      acc1 = fmaf(w0, __uint_as_float(g0 & 0xffff0000u), acc1);
      acc0 = fmaf(w1, __uint_as_float(g1 << 16), acc0);
      acc1 = fmaf(w1, __uint_as_float(g1 & 0xffff0000u), acc1);
      acc0 = fmaf(w2, __uint_as_float(g2 << 16), acc0);
      acc1 = fmaf(w2, __uint_as_float(g2 & 0xffff0000u), acc1);
      acc0 = fmaf(w3, __uint_as_float(g3 << 16), acc0);
      acc1 = fmaf(w3, __uint_as_float(g3 & 0xffff0000u), acc1);
      acc0 = fmaf(w4, __uint_as_float(g4 << 16), acc0);
      acc1 = fmaf(w4, __uint_as_float(g4 & 0xffff0000u), acc1);
      acc0 = fmaf(w5, __uint_as_float(g5 << 16), acc0);
      acc1 = fmaf(w5, __uint_as_float(g5 & 0xffff0000u), acc1);
      acc0 = fmaf(w6, __uint_as_float(g6 << 16), acc0);
      acc1 = fmaf(w6, __uint_as_float(g6 & 0xffff0000u), acc1);
      acc0 = fmaf(w7, __uint_as_float(g7 << 16), acc0);
      acc1 = fmaf(w7, __uint_as_float(g7 & 0xffff0000u), acc1);
    }
    for (; jj < m; ++jj) {
      const int s = __builtin_amdgcn_readlane(sidx, jj);
      const float w =
          __uint_as_float(__builtin_amdgcn_readlane(__float_as_uint(p), jj));
      const uint32 gv = Hh[s * 64 + lane];
      acc0 = fmaf(w, __uint_as_float(gv << 16), acc0);
      acc1 = fmaf(w, __uint_as_float(gv & 0xffff0000u), acc1);
    }
  }
  const float inv = 1.f / denom;
  float v0 = acc0 * inv + bias[c0];
  float v1 = acc1 * inv + bias[c1];
  const float sc0 = gam[c0] * rsqrtf(var[c0] + BNEPS);
  const float sc1 = gam[c1] * rsqrtf(var[c1] + BNEPS);
  v0 = fmaxf((v0 - mu[c0]) * sc0 + bet[c0], 0.f);
  v1 = fmaxf((v1 - mu[c1]) * sc1 + bet[c1], 0.f);
  Y[(long)wid * HD + c0] = v0;
  Y[(long)wid * HD + c1] = v1;
}

// ---------------- global mean pool + MLP head ----------------
__global__ __launch_bounds__(256)
void k_pool_head(const float* __restrict__ Y, const int* __restrict__ batch, int n,
                 const float* __restrict__ lw1, const float* __restrict__ lb1,
                 const float* __restrict__ lw2, const float* __restrict__ lb2,
                 float* __restrict__ out) {
  const int g = blockIdx.x;
  const int wave = threadIdx.x >> 6, lane = threadIdx.x & 63;
  int lo = 0, hi = n;
  while (lo < hi) { int mid = (lo + hi) >> 1; if (batch[mid] < g) lo = mid + 1; else hi = mid; }
  const int start = lo;
  hi = n;
  while (lo < hi) { int mid = (lo + hi) >> 1; if (batch[mid] < g + 1) lo = mid + 1; else hi = mid; }
  const int end = lo;
  const int c0 = lane * 2;
  float m0 = 0.f, m1 = 0.f;
  for (int i = start + wave; i < end; i += 4) {
    float2 hv = *(const float2*)&Y[(long)i * HD + c0];
    m0 += hv.x;
    m1 += hv.y;
  }
  __shared__ float red[4][HD];
  red[wave][c0] = m0;
  red[wave][c0 + 1] = m1;
  __syncthreads();
  if (wave == 0) {
    m0 = red[0][c0] + red[1][c0] + red[2][c0] + red[3][c0];
    m1 = red[0][c0 + 1] + red[1][c0 + 1] + red[2][c0 + 1] + red[3][c0 + 1];
    const float cnt = (float)(end - start);
    const float invc = (cnt > 0.f) ? 1.f / cnt : 0.f;
    m0 *= invc;
    m1 *= invc;
    float t0 = lb1[c0], t1 = lb1[c0 + 1];
    for (int k = 0; k < HD; ++k) {
      float pv = __shfl((k & 1) ? m1 : m0, k >> 1, 64);
      float2 w2 = *(const float2*)&lw1[k * HD + c0];
      t0 = fmaf(pv, w2.x, t0);
      t1 = fmaf(pv, w2.y, t1);
    }
    t0 = fmaxf(t0, 0.f);
    t1 = fmaxf(t1, 0.f);
    float p = t0 * lw2[c0] + t1 * lw2[c0 + 1];
#pragma unroll
    for (int off = 32; off; off >>= 1) p += __shfl_xor(p, off, 64);
    if (lane == 0) out[g] = p + lb2[0];
  }
}

// ---------------- launch ----------------

extern "C" void kernel_launch(void* const* d_in, const int* in_sizes, int n_in,
                              void* d_out, int out_size, void* d_ws, size_t ws_size,
                              hipStream_t stream) {
  const float* x = (const float*)d_in[0];
  const int* ei = (const int*)d_in[1];
  const int* batch = (const int*)d_in[2];
  const float* W1 = (const float*)d_in[3];
  const float* as1 = (const float*)d_in[4];
  const float* ad1 = (const float*)d_in[5];
  const float* b1 = (const float*)d_in[6];
  const float* W2 = (const float*)d_in[7];
  const float* as2 = (const float*)d_in[8];
  const float* ad2 = (const float*)d_in[9];
  const float* b2 = (const float*)d_in[10];
  const float* W3 = (const float*)d_in[11];
  const float* as3 = (const float*)d_in[12];
  const float* ad3 = (const float*)d_in[13];
  const float* b3 = (const float*)d_in[14];
  const float* g1 = (const float*)d_in[15];
  const float* be1 = (const float*)d_in[16];
  const float* m1 = (const float*)d_in[17];
  const float* v1 = (const float*)d_in[18];
  const float* g2 = (const float*)d_in[19];
  const float* be2 = (const float*)d_in[20];
  const float* m2 = (const float*)d_in[21];
  const float* v2 = (const float*)d_in[22];
  const float* g3 = (const float*)d_in[23];
  const float* be3 = (const float*)d_in[24];
  const float* m3 = (const float*)d_in[25];
  const float* v3 = (const float*)d_in[26];
  const float* lw1 = (const float*)d_in[27];
  const float* lb1 = (const float*)d_in[28];
  const float* lw2 = (const float*)d_in[29];
  const float* lb2 = (const float*)d_in[30];

  const int n = in_sizes[0] / 64;  // 50000
  const int E = in_sizes[1] / 2;   // 640000
  const int* src = ei;
  const int* dst = ei + E;

  // workspace carve (4B units)
  uint32* hbuf = (uint32*)d_ws;                 // n*64   (bf16x2 packed h)
  float* ybuf = (float*)(hbuf + (long)n * 64);  // n*128
  float* ssrc = ybuf + (long)n * HD;            // n
  float* sdstv = ssrc + n;                      // n
  int* deg = (int*)(sdstv + n);                 // n
  int* offs = deg + n;                          // n+1
  int* cursor = offs + n + 1;                   // n
  int* csr = cursor + n;                        // E+n
  int* part = csr + (E + n);                    // <=256
  uint32* PW1 = (uint32*)(part + 256);          // 8192 each
  uint32* PW2 = PW1 + 8192;
  uint32* PW3 = PW2 + 8192;

  const int B = 256;
  dim3 blk(B);
  const int nb = (n + B - 1) / B;

  // W pre-pack (independent of CSR build)
  k_packw<64><<<dim3(16), blk, 0, stream>>>(W1, PW1);
  k_packw<128><<<dim3(32), blk, 0, stream>>>(W2, PW2);
  k_packw<128><<<dim3(32), blk, 0, stream>>>(W3, PW3);

  // CSR build (reused by all 3 layers)
  k_init_deg<<<dim3(nb), blk, 0, stream>>>(deg, n);
  k_hist<<<dim3((E + B - 1) / B), blk, 0, stream>>>(dst, deg, E);
  k_scan_part<<<dim3(nb), blk, 0, stream>>>(deg, part, n);
  k_scan_part2<<<dim3(1), blk, 0, stream>>>(part, nb);
  k_scan_final<<<dim3(nb), blk, 0, stream>>>(deg, part, offs, n);
  k_fill_self<<<dim3(nb), blk, 0, stream>>>(offs, csr, cursor, n);
  k_fill_edges<<<dim3((E + B - 1) / B), blk, 0, stream>>>(src, dst, cursor, csr, E);

  const dim3 ggrid((n + 63) / 64);
  const dim3 agrid((n + 3) / 4);

  // layer 1
  k_gemm_mfma<64><<<ggrid, blk, 0, stream>>>(x, PW1, as1, ad1, hbuf, ssrc, sdstv, n);
  k_agg<<<agrid, blk, 0, stream>>>(hbuf, ssrc, sdstv, offs, csr, b1, g1, be1, m1, v1, ybuf, n);
  // layer 2
  k_gemm_mfma<128><<<ggrid, blk, 0, stream>>>(ybuf, PW2, as2, ad2, hbuf, ssrc, sdstv, n);
  k_agg<<<agrid, blk, 0, stream>>>(hbuf, ssrc, sdstv, offs, csr, b2, g2, be2, m2, v2, ybuf, n);
  // layer 3
  k_gemm_mfma<128><<<ggrid, blk, 0, stream>>>(ybuf, PW3, as3, ad3, hbuf, ssrc, sdstv, n);
  k_agg<<<agrid, blk, 0, stream>>>(hbuf, ssrc, sdstv, offs, csr, b3, g3, be3, m3, v3, ybuf, n);

  // pool + head
  k_pool_head<<<dim3(256), blk, 0, stream>>>(ybuf, batch, n, lw1, lb1, lw2, lb2,
                                             (float*)d_out);
}

// Round 4
// 252.681 us; speedup vs baseline: 2.6846x; 1.0611x over previous
//
#include <hip/hip_runtime.h>

#define HD 128
#define NEG 0.2f
#define BNEPS 1e-5f

typedef unsigned int uint32;
typedef __attribute__((ext_vector_type(8))) short short8;   // 8 bf16 (4 VGPRs)
typedef __attribute__((ext_vector_type(4))) float floatx4;  // MFMA acc

// ---------------- wave helpers ----------------

__device__ inline float wave_max_f(float v) {
#pragma unroll
  for (int off = 32; off; off >>= 1) v = fmaxf(v, __shfl_xor(v, off, 64));
  return v;
}
__device__ inline float wave_sum_f(float v) {
#pragma unroll
  for (int off = 32; off; off >>= 1) v += __shfl_xor(v, off, 64);
  return v;
}
__device__ inline int wave_sum_i(int v) {
#pragma unroll
  for (int off = 32; off; off >>= 1) v += __shfl_xor(v, off, 64);
  return v;
}
__device__ inline int wave_iscan_i(int v, int lane) {
#pragma unroll
  for (int off = 1; off < 64; off <<= 1) {
    int t = __shfl_up(v, off, 64);
    if (lane >= off) v += t;
  }
  return v;
}
__device__ inline uint32 f2bf(float f) {  // fp32 -> bf16 (RNE), low 16 bits
  uint32 u = __float_as_uint(f);
  return (u + 0x7fffu + ((u >> 16) & 1u)) >> 16;
}
// fragment k-pair for B-side packing. perm=false: linear k (fp32-staged A).
// perm=true: A comes from slot-layout bf16 Y; word w holds cols (q, q+16),
// q = (w>>4)*32 + (w&15); fragment word w = kc*16 + lg*4 + e2.
__device__ inline void kpair(int kc, int lg, int e2, bool perm, int& k_lo, int& k_hi) {
  if (!perm) {
    k_lo = kc * 32 + lg * 8 + e2 * 2;
    k_hi = k_lo + 1;
  } else {
    int w = kc * 16 + lg * 4 + e2;
    k_lo = ((w >> 4) << 5) + (w & 15);
    k_hi = k_lo + 16;
  }
}

// ---------------- CSR build ----------------

__global__ void k_init_deg(int* __restrict__ deg, int n) {
  int i = blockIdx.x * blockDim.x + threadIdx.x;
  if (i < n) deg[i] = 1;  // self-loop
}

__global__ void k_hist(const int* __restrict__ dst, int* __restrict__ deg, int E) {
  int i = blockIdx.x * blockDim.x + threadIdx.x;
  if (i < E) atomicAdd(&deg[dst[i]], 1);
}

__global__ __launch_bounds__(256) void k_scan_part(const int* __restrict__ deg,
                                                   int* __restrict__ part, int n) {
  const int t = threadIdx.x, lane = t & 63, wave = t >> 6;
  const int i = blockIdx.x * 256 + t;
  int v = (i < n) ? deg[i] : 0;
  int wv = wave_sum_i(v);
  __shared__ int ws[4];
  if (lane == 0) ws[wave] = wv;
  __syncthreads();
  if (t == 0) part[blockIdx.x] = ws[0] + ws[1] + ws[2] + ws[3];
}

__global__ __launch_bounds__(256) void k_scan_part2(int* __restrict__ part, int nb) {
  const int t = threadIdx.x, lane = t & 63, wave = t >> 6;
  int v = (t < nb) ? part[t] : 0;
  int x = wave_iscan_i(v, lane);
  __shared__ int ws[4];
  if (lane == 63) ws[wave] = x;
  __syncthreads();
  int add = 0;
#pragma unroll
  for (int w = 0; w < 4; ++w)
    if (w < wave) add += ws[w];
  x += add;
  if (t < nb) part[t] = x;  // inclusive scan of block sums
}

// final scan + fused self-loop fill (csr[offs[i]] = i, cursor = offs[i]+1)
__global__ __launch_bounds__(256) void k_scan_final(const int* __restrict__ deg,
                                                    const int* __restrict__ part,
                                                    int* __restrict__ offs,
                                                    int* __restrict__ csr,
                                                    int* __restrict__ cursor, int n) {
  const int t = threadIdx.x, lane = t & 63, wave = t >> 6;
  const int b = blockIdx.x;
  const int i = b * 256 + t;
  int v = (i < n) ? deg[i] : 0;
  int x = wave_iscan_i(v, lane);
  __shared__ int ws[4];
  if (lane == 63) ws[wave] = x;
  __syncthreads();
  int add = (b > 0) ? part[b - 1] : 0;
#pragma unroll
  for (int w = 0; w < 4; ++w)
    if (w < wave) add += ws[w];
  x += add;
  if (i < n) {
    const int excl = x - v;  // exclusive prefix = offs[i]
    offs[i + 1] = x;
    csr[excl] = i;
    cursor[i] = excl + 1;
  }
  if (i == 0) offs[0] = 0;
}

__global__ void k_fill_edges(const int* __restrict__ src, const int* __restrict__ dst,
                             int* __restrict__ cursor, int* __restrict__ csr, int E) {
  int i = blockIdx.x * blockDim.x + threadIdx.x;
  if (i < E) { int p = atomicAdd(&cursor[dst[i]], 1); csr[p] = src[i]; }
}

// ---------------- combined pack: PW (B fragments) + wa score fragments ----------------
// blocks 0..15: PW1 (K=64, linear); 16..47: PW2 (K=128, perm); 48..79: PW3 (perm);
// 80..82: wa_s/wa_d = W @ a  ->  score B-fragments (col0 = wa_s, col1 = wa_d).
__global__ __launch_bounds__(256)
void k_pack(const float* __restrict__ W1, const float* __restrict__ as1v,
            const float* __restrict__ ad1v, const float* __restrict__ W2,
            const float* __restrict__ as2v, const float* __restrict__ ad2v,
            const float* __restrict__ W3, const float* __restrict__ as3v,
            const float* __restrict__ ad3v, uint32* __restrict__ PW1,
            uint32* __restrict__ PW2, uint32* __restrict__ PW3,
            uint32* __restrict__ BFA1, uint32* __restrict__ BFA2,
            uint32* __restrict__ BFA3) {
  const int b = blockIdx.x, t = threadIdx.x;
  if (b < 80) {
    const float* W;
    uint32* PW;
    int KC, local;
    bool perm;
    if (b < 16) { W = W1; PW = PW1; KC = 2; perm = false; local = b; }
    else if (b < 48) { W = W2; PW = PW2; KC = 4; perm = true; local = b - 16; }
    else { W = W3; PW = PW3; KC = 4; perm = true; local = b - 48; }
    const int idx = local * 256 + t;
    const int e2 = idx & 3, l = (idx >> 2) & 63, f = idx >> 8;
    const int kc = f % KC, ct = f / KC;
    int k_lo, k_hi;
    kpair(kc, l >> 4, e2, perm, k_lo, k_hi);
    const int col = ct * 16 + (l & 15);
    PW[idx] = f2bf(W[k_lo * HD + col]) | (f2bf(W[k_hi * HD + col]) << 16);
  } else {
    const int layer = b - 80;
    const float* W = layer == 0 ? W1 : layer == 1 ? W2 : W3;
    const float* av = layer == 0 ? as1v : layer == 1 ? as2v : as3v;
    const float* dv = layer == 0 ? ad1v : layer == 1 ? ad2v : ad3v;
    uint32* BFA = layer == 0 ? BFA1 : layer == 1 ? BFA2 : BFA3;
    const int K = layer == 0 ? 64 : 128, KC = K / 32;
    const bool perm = layer != 0;
    __shared__ float ws[128], wd[128];
    if (t < K) {
      float s = 0.f, d = 0.f;
      for (int j = 0; j < HD; ++j) {
        const float w = W[t * HD + j];
        s = fmaf(w, av[j], s);
        d = fmaf(w, dv[j], d);
      }
      ws[t] = s;
      wd[t] = d;
    }
    __syncthreads();
    const int total = KC * 256;  // KC*64*4 uint32 words
    for (int idx = t; idx < total; idx += 256) {
      const int e2 = idx & 3, l = (idx >> 2) & 63, kc = idx >> 8;
      int k_lo, k_hi;
      kpair(kc, l >> 4, e2, perm, k_lo, k_hi);
      const int li = l & 15;
      const float lo = li == 0 ? ws[k_lo] : li == 1 ? wd[k_lo] : 0.f;
      const float hi = li == 0 ? ws[k_hi] : li == 1 ? wd[k_hi] : 0.f;
      BFA[idx] = f2bf(lo) | (f2bf(hi) << 16);
    }
  }
}

// ---------------- MFMA GEMM ----------------
// h = X @ W via mfma_f32_16x16x32_bf16. Block = 64 rows; 4 waves split 128 cols.
// Scores via wave-0 MFMA against BFA (cols 0/1 = W@a_s, W@a_d) -- no shuffles.
// BF16IN: X is packed bf16 slot-layout (Ybf); else fp32 row-major.
// Hh written packed bf16x2 slot layout: word w = wv*16+(l&15) holds cols (q, q+16),
// q = (w>>4)*32 + (w&15).
template <int K, bool BF16IN>
__global__ __launch_bounds__(256)
void k_gemm_mfma(const void* __restrict__ Xv, const uint32* __restrict__ PW,
                 const uint32* __restrict__ BFA, uint32* __restrict__ Hh,
                 float* __restrict__ ssrc, float* __restrict__ sdst, int n) {
  constexpr int KC = K / 32;
  __shared__ uint32 Xl[64 * K / 2];
  const int t = threadIdx.x;
  const int wv = t >> 6, l = t & 63;
  const int rowbase = blockIdx.x * 64;

  // B fragments -> registers
  short8 bfr[2][KC];
#pragma unroll
  for (int c2 = 0; c2 < 2; ++c2)
#pragma unroll
    for (int kc = 0; kc < KC; ++kc)
      bfr[c2][kc] = *((const short8*)PW + ((wv * 2 + c2) * KC + kc) * 64 + l);
  short8 bfa[KC];
  if (wv == 0) {
#pragma unroll
    for (int kc = 0; kc < KC; ++kc) bfa[kc] = *((const short8*)BFA + kc * 64 + l);
  }

  // stage X -> LDS (bf16, XOR-swizzled: byte ^ ((row&7)<<4))
  if (BF16IN) {
    const uint32* Xb = (const uint32*)Xv;
    // 16B blocks: 64 rows x (K/8); swizzle on block index low 3 bits
#pragma unroll
    for (int B = t; B < 64 * (K / 8); B += 256) {
      const int row = B / (K / 8), cb = B % (K / 8);
      const int r = min(rowbase + row, n - 1);
      const uint4 v = *(const uint4*)&Xb[(long)r * (K / 2) + cb * 4];
      *(uint4*)&Xl[row * (K / 2) + (cb ^ (row & 7)) * 4] = v;
    }
  } else {
    const float* X = (const float*)Xv;
    const int PAIRS = 64 * K / 2;
    for (int i = t; i < PAIRS; i += 256) {
      const int row = i / (K / 2), kp = i % (K / 2);
      const int r = min(rowbase + row, n - 1);
      const float2 v = *(const float2*)&X[(long)r * K + kp * 2];
      int byte = row * (K * 2) + kp * 4;
      byte ^= (row & 7) << 4;
      Xl[byte >> 2] = f2bf(v.x) | (f2bf(v.y) << 16);
    }
  }
  __syncthreads();

  floatx4 acc[4][2], acc2[4];
#pragma unroll
  for (int rt = 0; rt < 4; ++rt) {
    acc[rt][0] = (floatx4){0.f, 0.f, 0.f, 0.f};
    acc[rt][1] = (floatx4){0.f, 0.f, 0.f, 0.f};
    acc2[rt] = (floatx4){0.f, 0.f, 0.f, 0.f};
  }
  const int row_l = l & 15, kgrp = l >> 4;
#pragma unroll
  for (int rt = 0; rt < 4; ++rt) {
    const int row = rt * 16 + row_l;
#pragma unroll
    for (int kc = 0; kc < KC; ++kc) {
      const int byte = (row * (K * 2) + kc * 64 + kgrp * 16) ^ ((row & 7) << 4);
      const short8 af = *(const short8*)((const char*)Xl + byte);
      acc[rt][0] = __builtin_amdgcn_mfma_f32_16x16x32_bf16(af, bfr[0][kc], acc[rt][0], 0, 0, 0);
      acc[rt][1] = __builtin_amdgcn_mfma_f32_16x16x32_bf16(af, bfr[1][kc], acc[rt][1], 0, 0, 0);
      if (wv == 0)
        acc2[rt] = __builtin_amdgcn_mfma_f32_16x16x32_bf16(af, bfa[kc], acc2[rt], 0, 0, 0);
    }
  }

  // epilogue: packed bf16 h store + direct score stores (wave 0, cols 0/1)
#pragma unroll
  for (int rt = 0; rt < 4; ++rt) {
#pragma unroll
    for (int r = 0; r < 4; ++r) {
      const int R = rowbase + rt * 16 + kgrp * 4 + r;
      if (R < n)
        Hh[(long)R * 64 + wv * 16 + row_l] =
            f2bf(acc[rt][0][r]) | (f2bf(acc[rt][1][r]) << 16);
    }
  }
  if (wv == 0 && row_l < 2) {
    float* tgt = (row_l == 0) ? ssrc : sdst;
#pragma unroll
    for (int rt = 0; rt < 4; ++rt)
#pragma unroll
      for (int r = 0; r < 4; ++r) {
        const int R = rowbase + rt * 16 + kgrp * 4 + r;
        if (R < n) tgt[R] = acc2[rt][r];
      }
  }
}

// ---------------- per-dst-node softmax aggregation ----------------
// One wave per dst node; slot-layout cols: c0=(lane>>4)*32+(lane&15), c1=c0+16.
// Output Ybf: packed bf16 pair (v0,v1) at word = lane (same slot layout as Hh).
__global__ __launch_bounds__(256)
void k_agg(const uint32* __restrict__ Hh, const float* __restrict__ ssrc,
           const float* __restrict__ sdst, const int* __restrict__ offs,
           const int* __restrict__ csr, const float* __restrict__ bias,
           const float* __restrict__ gam, const float* __restrict__ bet,
           const float* __restrict__ mu, const float* __restrict__ var,
           uint32* __restrict__ Ybf, int n) {
  const int wid = (blockIdx.x * blockDim.x + threadIdx.x) >> 6;
  const int lane = threadIdx.x & 63;
  if (wid >= n) return;
  const int s0 = offs[wid], s1 = offs[wid + 1];
  const float sdv = sdst[wid];
  const int c0 = (lane >> 4) * 32 + (lane & 15);
  const int c1 = c0 + 16;
  float acc0 = 0.f, acc1 = 0.f, denom = 0.f, mx = -1e30f;
  for (int base = s0; base < s1; base += 64) {
    const int m = min(64, s1 - base);
    int sidx = 0;
    float e = -1e30f;
    if (lane < m) {
      sidx = csr[base + lane];
      float tt = ssrc[sidx] + sdv;
      e = (tt > 0.f) ? tt : NEG * tt;
    }
    const float cmx = wave_max_f(e);
    const float nmx = fmaxf(mx, cmx);
    if (nmx > mx) {
      const float sc = __expf(mx - nmx);
      acc0 *= sc; acc1 *= sc; denom *= sc;
      mx = nmx;
    }
    const float p = (lane < m) ? __expf(e - mx) : 0.f;
    denom += wave_sum_f(p);
    int jj = 0;
    for (; jj + 8 <= m; jj += 8) {
      const int i0 = __builtin_amdgcn_readlane(sidx, jj + 0);
      const int i1 = __builtin_amdgcn_readlane(sidx, jj + 1);
      const int i2 = __builtin_amdgcn_readlane(sidx, jj + 2);
      const int i3 = __builtin_amdgcn_readlane(sidx, jj + 3);
      const int i4 = __builtin_amdgcn_readlane(sidx, jj + 4);
      const int i5 = __builtin_amdgcn_readlane(sidx, jj + 5);
      const int i6 = __builtin_amdgcn_readlane(sidx, jj + 6);
      const int i7 = __builtin_amdgcn_readlane(sidx, jj + 7);
      const uint32 pu = __float_as_uint(p);
      const float w0 = __uint_as_float(__builtin_amdgcn_readlane(pu, jj + 0));
      const float w1 = __uint_as_float(__builtin_amdgcn_readlane(pu, jj + 1));
      const float w2 = __uint_as_float(__builtin_amdgcn_readlane(pu, jj + 2));
      const float w3 = __uint_as_float(__builtin_amdgcn_readlane(pu, jj + 3));
      const float w4 = __uint_as_float(__builtin_amdgcn_readlane(pu, jj + 4));
      const float w5 = __uint_as_float(__builtin_amdgcn_readlane(pu, jj + 5));
      const float w6 = __uint_as_float(__builtin_amdgcn_readlane(pu, jj + 6));
      const float w7 = __uint_as_float(__builtin_amdgcn_readlane(pu, jj + 7));
      const uint32 g0 = Hh[i0 * 64 + lane];
      const uint32 g1 = Hh[i1 * 64 + lane];
      const uint32 g2 = Hh[i2 * 64 + lane];
      const uint32 g3 = Hh[i3 * 64 + lane];
      const uint32 g4 = Hh[i4 * 64 + lane];
      const uint32 g5 = Hh[i5 * 64 + lane];
      const uint32 g6 = Hh[i6 * 64 + lane];
      const uint32 g7 = Hh[i7 * 64 + lane];
      acc0 = fmaf(w0, __uint_as_float(g0 << 16), acc0);
      acc1 = fmaf(w0, __uint_as_float(g0 & 0xffff0000u), acc1);
      acc0 = fmaf(w1, __uint_as_float(g1 << 16), acc0);
      acc1 = fmaf(w1, __uint_as_float(g1 & 0xffff0000u), acc1);
      acc0 = fmaf(w2, __uint_as_float(g2 << 16), acc0);
      acc1 = fmaf(w2, __uint_as_float(g2 & 0xffff0000u), acc1);
      acc0 = fmaf(w3, __uint_as_float(g3 << 16), acc0);
      acc1 = fmaf(w3, __uint_as_float(g3 & 0xffff0000u), acc1);
      acc0 = fmaf(w4, __uint_as_float(g4 << 16), acc0);
      acc1 = fmaf(w4, __uint_as_float(g4 & 0xffff0000u), acc1);
      acc0 = fmaf(w5, __uint_as_float(g5 << 16), acc0);
      acc1 = fmaf(w5, __uint_as_float(g5 & 0xffff0000u), acc1);
      acc0 = fmaf(w6, __uint_as_float(g6 << 16), acc0);
      acc1 = fmaf(w6, __uint_as_float(g6 & 0xffff0000u), acc1);
      acc0 = fmaf(w7, __uint_as_float(g7 << 16), acc0);
      acc1 = fmaf(w7, __uint_as_float(g7 & 0xffff0000u), acc1);
    }
    for (; jj < m; ++jj) {
      const int s = __builtin_amdgcn_readlane(sidx, jj);
      const float w =
          __uint_as_float(__builtin_amdgcn_readlane(__float_as_uint(p), jj));
      const uint32 gv = Hh[s * 64 + lane];
      acc0 = fmaf(w, __uint_as_float(gv << 16), acc0);
      acc1 = fmaf(w, __uint_as_float(gv & 0xffff0000u), acc1);
    }
  }
  const float inv = 1.f / denom;
  float v0 = acc0 * inv + bias[c0];
  float v1 = acc1 * inv + bias[c1];
  const float sc0 = gam[c0] * rsqrtf(var[c0] + BNEPS);
  const float sc1 = gam[c1] * rsqrtf(var[c1] + BNEPS);
  v0 = fmaxf((v0 - mu[c0]) * sc0 + bet[c0], 0.f);
  v1 = fmaxf((v1 - mu[c1]) * sc1 + bet[c1], 0.f);
  Ybf[(long)wid * 64 + lane] = f2bf(v0) | (f2bf(v1) << 16);
}

// ---------------- global mean pool + MLP head (bf16 Y, slot layout) ----------------
__global__ __launch_bounds__(256)
void k_pool_head(const uint32* __restrict__ Ybf, const int* __restrict__ batch, int n,
                 const float* __restrict__ lw1, const float* __restrict__ lb1,
                 const float* __restrict__ lw2, const float* __restrict__ lb2,
                 float* __restrict__ out) {
  const int g = blockIdx.x;
  const int wave = threadIdx.x >> 6, lane = threadIdx.x & 63;
  int lo = 0, hi = n;
  while (lo < hi) { int mid = (lo + hi) >> 1; if (batch[mid] < g) lo = mid + 1; else hi = mid; }
  const int start = lo;
  hi = n;
  while (lo < hi) { int mid = (lo + hi) >> 1; if (batch[mid] < g + 1) lo = mid + 1; else hi = mid; }
  const int end = lo;
  const int c0 = (lane >> 4) * 32 + (lane & 15);
  const int c1 = c0 + 16;
  float m0 = 0.f, m1 = 0.f;
  for (int i = start + wave; i < end; i += 4) {
    const uint32 gv = Ybf[(long)i * 64 + lane];
    m0 += __uint_as_float(gv << 16);
    m1 += __uint_as_float(gv & 0xffff0000u);
  }
  __shared__ float red[4][HD];
  red[wave][c0] = m0;
  red[wave][c1] = m1;
  __syncthreads();
  if (wave == 0) {
    m0 = red[0][c0] + red[1][c0] + red[2][c0] + red[3][c0];
    m1 = red[0][c1] + red[1][c1] + red[2][c1] + red[3][c1];
    const float cnt = (float)(end - start);
    const float invc = (cnt > 0.f) ? 1.f / cnt : 0.f;
    m0 *= invc;
    m1 *= invc;
    float t0 = lb1[c0], t1 = lb1[c1];
    for (int k = 0; k < HD; ++k) {
      const int srcl = ((k >> 5) << 4) + (k & 15);
      const float pv = __shfl(((k >> 4) & 1) ? m1 : m0, srcl, 64);
      t0 = fmaf(pv, lw1[k * HD + c0], t0);
      t1 = fmaf(pv, lw1[k * HD + c1], t1);
    }
    t0 = fmaxf(t0, 0.f);
    t1 = fmaxf(t1, 0.f);
    float p = t0 * lw2[c0] + t1 * lw2[c1];
#pragma unroll
    for (int off = 32; off; off >>= 1) p += __shfl_xor(p, off, 64);
    if (lane == 0) out[g] = p + lb2[0];
  }
}

// ---------------- launch ----------------

extern "C" void kernel_launch(void* const* d_in, const int* in_sizes, int n_in,
                              void* d_out, int out_size, void* d_ws, size_t ws_size,
                              hipStream_t stream) {
  const float* x = (const float*)d_in[0];
  const int* ei = (const int*)d_in[1];
  const int* batch = (const int*)d_in[2];
  const float* W1 = (const float*)d_in[3];
  const float* as1 = (const float*)d_in[4];
  const float* ad1 = (const float*)d_in[5];
  const float* b1 = (const float*)d_in[6];
  const float* W2 = (const float*)d_in[7];
  const float* as2 = (const float*)d_in[8];
  const float* ad2 = (const float*)d_in[9];
  const float* b2 = (const float*)d_in[10];
  const float* W3 = (const float*)d_in[11];
  const float* as3 = (const float*)d_in[12];
  const float* ad3 = (const float*)d_in[13];
  const float* b3 = (const float*)d_in[14];
  const float* g1 = (const float*)d_in[15];
  const float* be1 = (const float*)d_in[16];
  const float* m1 = (const float*)d_in[17];
  const float* v1 = (const float*)d_in[18];
  const float* g2 = (const float*)d_in[19];
  const float* be2 = (const float*)d_in[20];
  const float* m2 = (const float*)d_in[21];
  const float* v2 = (const float*)d_in[22];
  const float* g3 = (const float*)d_in[23];
  const float* be3 = (const float*)d_in[24];
  const float* m3 = (const float*)d_in[25];
  const float* v3 = (const float*)d_in[26];
  const float* lw1 = (const float*)d_in[27];
  const float* lb1 = (const float*)d_in[28];
  const float* lw2 = (const float*)d_in[29];
  const float* lb2 = (const float*)d_in[30];

  const int n = in_sizes[0] / 64;  // 50000
  const int E = in_sizes[1] / 2;   // 640000
  const int* src = ei;
  const int* dst = ei + E;

  // workspace carve (4B units)
  uint32* hbuf = (uint32*)d_ws;        // n*64 (bf16x2 packed h)
  uint32* ybuf = hbuf + (long)n * 64;  // n*64 (bf16x2 packed y)
  float* ssrc = (float*)(ybuf + (long)n * 64);  // n
  float* sdstv = ssrc + n;             // n
  int* deg = (int*)(sdstv + n);        // n
  int* offs = deg + n;                 // n+1
  int* cursor = offs + n + 1;          // n
  int* csr = cursor + n;               // E+n
  int* part = csr + (E + n);           // <=256
  uint32* PW1 = (uint32*)(part + 256); // 4096
  uint32* PW2 = PW1 + 4096;            // 8192
  uint32* PW3 = PW2 + 8192;            // 8192
  uint32* BFA1 = PW3 + 8192;           // 512
  uint32* BFA2 = BFA1 + 512;           // 1024
  uint32* BFA3 = BFA2 + 1024;          // 1024

  const int B = 256;
  dim3 blk(B);
  const int nb = (n + B - 1) / B;

  // pack everything (PW + score fragments) in one kernel
  k_pack<<<dim3(83), blk, 0, stream>>>(W1, as1, ad1, W2, as2, ad2, W3, as3, ad3,
                                       PW1, PW2, PW3, BFA1, BFA2, BFA3);

  // CSR build (reused by all 3 layers)
  k_init_deg<<<dim3(nb), blk, 0, stream>>>(deg, n);
  k_hist<<<dim3((E + B - 1) / B), blk, 0, stream>>>(dst, deg, E);
  k_scan_part<<<dim3(nb), blk, 0, stream>>>(deg, part, n);
  k_scan_part2<<<dim3(1), blk, 0, stream>>>(part, nb);
  k_scan_final<<<dim3(nb), blk, 0, stream>>>(deg, part, offs, csr, cursor, n);
  k_fill_edges<<<dim3((E + B - 1) / B), blk, 0, stream>>>(src, dst, cursor, csr, E);

  const dim3 ggrid((n + 63) / 64);
  const dim3 agrid((n + 3) / 4);

  // layer 1
  k_gemm_mfma<64, false><<<ggrid, blk, 0, stream>>>(x, PW1, BFA1, hbuf, ssrc, sdstv, n);
  k_agg<<<agrid, blk, 0, stream>>>(hbuf, ssrc, sdstv, offs, csr, b1, g1, be1, m1, v1, ybuf, n);
  // layer 2
  k_gemm_mfma<128, true><<<ggrid, blk, 0, stream>>>(ybuf, PW2, BFA2, hbuf, ssrc, sdstv, n);
  k_agg<<<agrid, blk, 0, stream>>>(hbuf, ssrc, sdstv, offs, csr, b2, g2, be2, m2, v2, ybuf, n);
  // layer 3
  k_gemm_mfma<128, true><<<ggrid, blk, 0, stream>>>(ybuf, PW3, BFA3, hbuf, ssrc, sdstv, n);
  k_agg<<<agrid, blk, 0, stream>>>(hbuf, ssrc, sdstv, offs, csr, b3, g3, be3, m3, v3, ybuf, n);

  // pool + head
  k_pool_head<<<dim3(256), blk, 0, stream>>>(ybuf, batch, n, lw1, lb1, lw2, lb2,
                                             (float*)d_out);
}

// Round 5
// 242.602 us; speedup vs baseline: 2.7961x; 1.0415x over previous
//
#include <hip/hip_runtime.h>

#define HD 128
#define NEG 0.2f
#define BNEPS 1e-5f

typedef unsigned int uint32;
typedef __attribute__((ext_vector_type(8))) short short8;   // 8 bf16 (4 VGPRs)
typedef __attribute__((ext_vector_type(4))) float floatx4;  // MFMA acc

// ---------------- wave helpers ----------------

__device__ inline float wave_max_f(float v) {
#pragma unroll
  for (int off = 32; off; off >>= 1) v = fmaxf(v, __shfl_xor(v, off, 64));
  return v;
}
__device__ inline float wave_sum_f(float v) {
#pragma unroll
  for (int off = 32; off; off >>= 1) v += __shfl_xor(v, off, 64);
  return v;
}
__device__ inline int wave_sum_i(int v) {
#pragma unroll
  for (int off = 32; off; off >>= 1) v += __shfl_xor(v, off, 64);
  return v;
}
__device__ inline int wave_iscan_i(int v, int lane) {
#pragma unroll
  for (int off = 1; off < 64; off <<= 1) {
    int t = __shfl_up(v, off, 64);
    if (lane >= off) v += t;
  }
  return v;
}
__device__ inline uint32 f2bf(float f) {  // fp32 -> bf16 (RNE), low 16 bits
  uint32 u = __float_as_uint(f);
  return (u + 0x7fffu + ((u >> 16) & 1u)) >> 16;
}
// fragment k-pair for B-side packing. perm=false: linear k (fp32-staged A).
// perm=true: A comes from slot-layout bf16 Y; word w holds cols (q, q+16),
// q = (w>>4)*32 + (w&15); fragment word w = kc*16 + lg*4 + e2.
__device__ inline void kpair(int kc, int lg, int e2, bool perm, int& k_lo, int& k_hi) {
  if (!perm) {
    k_lo = kc * 32 + lg * 8 + e2 * 2;
    k_hi = k_lo + 1;
  } else {
    int w = kc * 16 + lg * 4 + e2;
    k_lo = ((w >> 4) << 5) + (w & 15);
    k_hi = k_lo + 16;
  }
}

// ---------------- CSR build ----------------
// deg[] is zeroed via hipMemsetAsync; hist counts edges; scans add +1 (self-loop).

__global__ void k_hist(const int* __restrict__ dst, int* __restrict__ deg, int E) {
  int i = blockIdx.x * blockDim.x + threadIdx.x;
  if (i < E) atomicAdd(&deg[dst[i]], 1);
}

__global__ __launch_bounds__(256) void k_scan_part(const int* __restrict__ deg,
                                                   int* __restrict__ part, int n) {
  const int t = threadIdx.x, lane = t & 63, wave = t >> 6;
  const int i = blockIdx.x * 256 + t;
  int v = (i < n) ? (deg[i] + 1) : 0;
  int wv = wave_sum_i(v);
  __shared__ int ws[4];
  if (lane == 0) ws[wave] = wv;
  __syncthreads();
  if (t == 0) part[blockIdx.x] = ws[0] + ws[1] + ws[2] + ws[3];
}

__global__ __launch_bounds__(256) void k_scan_part2(int* __restrict__ part, int nb) {
  const int t = threadIdx.x, lane = t & 63, wave = t >> 6;
  int v = (t < nb) ? part[t] : 0;
  int x = wave_iscan_i(v, lane);
  __shared__ int ws[4];
  if (lane == 63) ws[wave] = x;
  __syncthreads();
  int add = 0;
#pragma unroll
  for (int w = 0; w < 4; ++w)
    if (w < wave) add += ws[w];
  x += add;
  if (t < nb) part[t] = x;  // inclusive scan of block sums
}

// final scan + fused self-loop fill (csr[offs[i]] = i, cursor = offs[i]+1)
__global__ __launch_bounds__(256) void k_scan_final(const int* __restrict__ deg,
                                                    const int* __restrict__ part,
                                                    int* __restrict__ offs,
                                                    int* __restrict__ csr,
                                                    int* __restrict__ cursor, int n) {
  const int t = threadIdx.x, lane = t & 63, wave = t >> 6;
  const int b = blockIdx.x;
  const int i = b * 256 + t;
  int v = (i < n) ? (deg[i] + 1) : 0;
  int x = wave_iscan_i(v, lane);
  __shared__ int ws[4];
  if (lane == 63) ws[wave] = x;
  __syncthreads();
  int add = (b > 0) ? part[b - 1] : 0;
#pragma unroll
  for (int w = 0; w < 4; ++w)
    if (w < wave) add += ws[w];
  x += add;
  if (i < n) {
    const int excl = x - v;  // exclusive prefix = offs[i]
    offs[i + 1] = x;
    csr[excl] = i;
    cursor[i] = excl + 1;
  }
  if (i == 0) offs[0] = 0;
}

__global__ void k_fill_edges(const int* __restrict__ src, const int* __restrict__ dst,
                             int* __restrict__ cursor, int* __restrict__ csr, int E) {
  int i = blockIdx.x * blockDim.x + threadIdx.x;
  if (i < E) { int p = atomicAdd(&cursor[dst[i]], 1); csr[p] = src[i]; }
}

// ---------------- combined pack: PW (B fragments) + wa score fragments ----------------
// blocks 0..15: PW1 (K=64, linear); 16..47: PW2 (K=128, perm); 48..79: PW3 (perm);
// 80..82: wa_s/wa_d = W @ a  ->  score B-fragments (col0 = wa_s, col1 = wa_d).
__global__ __launch_bounds__(256)
void k_pack(const float* __restrict__ W1, const float* __restrict__ as1v,
            const float* __restrict__ ad1v, const float* __restrict__ W2,
            const float* __restrict__ as2v, const float* __restrict__ ad2v,
            const float* __restrict__ W3, const float* __restrict__ as3v,
            const float* __restrict__ ad3v, uint32* __restrict__ PW1,
            uint32* __restrict__ PW2, uint32* __restrict__ PW3,
            uint32* __restrict__ BFA1, uint32* __restrict__ BFA2,
            uint32* __restrict__ BFA3) {
  const int b = blockIdx.x, t = threadIdx.x;
  if (b < 80) {
    const float* W;
    uint32* PW;
    int KC, local;
    bool perm;
    if (b < 16) { W = W1; PW = PW1; KC = 2; perm = false; local = b; }
    else if (b < 48) { W = W2; PW = PW2; KC = 4; perm = true; local = b - 16; }
    else { W = W3; PW = PW3; KC = 4; perm = true; local = b - 48; }
    const int idx = local * 256 + t;
    const int e2 = idx & 3, l = (idx >> 2) & 63, f = idx >> 8;
    const int kc = f % KC, ct = f / KC;
    int k_lo, k_hi;
    kpair(kc, l >> 4, e2, perm, k_lo, k_hi);
    const int col = ct * 16 + (l & 15);
    PW[idx] = f2bf(W[k_lo * HD + col]) | (f2bf(W[k_hi * HD + col]) << 16);
  } else {
    const int layer = b - 80;
    const float* W = layer == 0 ? W1 : layer == 1 ? W2 : W3;
    const float* av = layer == 0 ? as1v : layer == 1 ? as2v : as3v;
    const float* dv = layer == 0 ? ad1v : layer == 1 ? ad2v : ad3v;
    uint32* BFA = layer == 0 ? BFA1 : layer == 1 ? BFA2 : BFA3;
    const int K = layer == 0 ? 64 : 128, KC = K / 32;
    const bool perm = layer != 0;
    __shared__ float ws[128], wd[128];
    if (t < K) {
      float s = 0.f, d = 0.f;
      for (int j = 0; j < HD; ++j) {
        const float w = W[t * HD + j];
        s = fmaf(w, av[j], s);
        d = fmaf(w, dv[j], d);
      }
      ws[t] = s;
      wd[t] = d;
    }
    __syncthreads();
    const int total = KC * 256;  // KC*64*4 uint32 words
    for (int idx = t; idx < total; idx += 256) {
      const int e2 = idx & 3, l = (idx >> 2) & 63, kc = idx >> 8;
      int k_lo, k_hi;
      kpair(kc, l >> 4, e2, perm, k_lo, k_hi);
      const int li = l & 15;
      const float lo = li == 0 ? ws[k_lo] : li == 1 ? wd[k_lo] : 0.f;
      const float hi = li == 0 ? ws[k_hi] : li == 1 ? wd[k_hi] : 0.f;
      BFA[idx] = f2bf(lo) | (f2bf(hi) << 16);
    }
  }
}

// ---------------- MFMA GEMM ----------------
// h = X @ W via mfma_f32_16x16x32_bf16. Block = 64 rows; 4 waves split 128 cols.
// Scores via wave-0 MFMA against BFA (cols 0/1 = W@a_s, W@a_d) -- no shuffles.
// BF16IN: X is packed bf16 slot-layout (Ybf); else fp32 row-major.
// Hh written packed bf16x2 slot layout: word w = wv*16+(l&15) holds cols (q, q+16),
// q = (w>>4)*32 + (w&15).
template <int K, bool BF16IN>
__global__ __launch_bounds__(256)
void k_gemm_mfma(const void* __restrict__ Xv, const uint32* __restrict__ PW,
                 const uint32* __restrict__ BFA, uint32* __restrict__ Hh,
                 float* __restrict__ ssrc, float* __restrict__ sdst, int n) {
  constexpr int KC = K / 32;
  __shared__ uint32 Xl[64 * K / 2];
  const int t = threadIdx.x;
  const int wv = t >> 6, l = t & 63;
  const int rowbase = blockIdx.x * 64;

  // B fragments -> registers
  short8 bfr[2][KC];
#pragma unroll
  for (int c2 = 0; c2 < 2; ++c2)
#pragma unroll
    for (int kc = 0; kc < KC; ++kc)
      bfr[c2][kc] = *((const short8*)PW + ((wv * 2 + c2) * KC + kc) * 64 + l);
  short8 bfa[KC];
  if (wv == 0) {
#pragma unroll
    for (int kc = 0; kc < KC; ++kc) bfa[kc] = *((const short8*)BFA + kc * 64 + l);
  }

  // stage X -> LDS (bf16, XOR-swizzled: byte ^ ((row&7)<<4))
  if (BF16IN) {
    const uint32* Xb = (const uint32*)Xv;
#pragma unroll
    for (int B = t; B < 64 * (K / 8); B += 256) {
      const int row = B / (K / 8), cb = B % (K / 8);
      const int r = min(rowbase + row, n - 1);
      const uint4 v = *(const uint4*)&Xb[(long)r * (K / 2) + cb * 4];
      *(uint4*)&Xl[row * (K / 2) + (cb ^ (row & 7)) * 4] = v;
    }
  } else {
    const float* X = (const float*)Xv;
    for (int i = t; i < 64 * (K / 4); i += 256) {
      const int row = i / (K / 4), kq = i % (K / 4);
      const int r = min(rowbase + row, n - 1);
      const float4 v = *(const float4*)&X[(long)r * K + kq * 4];
      uint2 p;
      p.x = f2bf(v.x) | (f2bf(v.y) << 16);
      p.y = f2bf(v.z) | (f2bf(v.w) << 16);
      int byte = row * (K * 2) + kq * 8;
      byte ^= (row & 7) << 4;
      *(uint2*)((char*)Xl + byte) = p;
    }
  }
  __syncthreads();

  floatx4 acc[4][2], acc2[4];
#pragma unroll
  for (int rt = 0; rt < 4; ++rt) {
    acc[rt][0] = (floatx4){0.f, 0.f, 0.f, 0.f};
    acc[rt][1] = (floatx4){0.f, 0.f, 0.f, 0.f};
    acc2[rt] = (floatx4){0.f, 0.f, 0.f, 0.f};
  }
  const int row_l = l & 15, kgrp = l >> 4;
#pragma unroll
  for (int rt = 0; rt < 4; ++rt) {
    const int row = rt * 16 + row_l;
#pragma unroll
    for (int kc = 0; kc < KC; ++kc) {
      const int byte = (row * (K * 2) + kc * 64 + kgrp * 16) ^ ((row & 7) << 4);
      const short8 af = *(const short8*)((const char*)Xl + byte);
      acc[rt][0] = __builtin_amdgcn_mfma_f32_16x16x32_bf16(af, bfr[0][kc], acc[rt][0], 0, 0, 0);
      acc[rt][1] = __builtin_amdgcn_mfma_f32_16x16x32_bf16(af, bfr[1][kc], acc[rt][1], 0, 0, 0);
      if (wv == 0)
        acc2[rt] = __builtin_amdgcn_mfma_f32_16x16x32_bf16(af, bfa[kc], acc2[rt], 0, 0, 0);
    }
  }

  // epilogue: packed bf16 h store + direct score stores (wave 0, cols 0/1)
#pragma unroll
  for (int rt = 0; rt < 4; ++rt) {
#pragma unroll
    for (int r = 0; r < 4; ++r) {
      const int R = rowbase + rt * 16 + kgrp * 4 + r;
      if (R < n)
        Hh[(long)R * 64 + wv * 16 + row_l] =
            f2bf(acc[rt][0][r]) | (f2bf(acc[rt][1][r]) << 16);
    }
  }
  if (wv == 0 && row_l < 2) {
    float* tgt = (row_l == 0) ? ssrc : sdst;
#pragma unroll
    for (int rt = 0; rt < 4; ++rt)
#pragma unroll
      for (int r = 0; r < 4; ++r) {
        const int R = rowbase + rt * 16 + kgrp * 4 + r;
        if (R < n) tgt[R] = acc2[rt][r];
      }
  }
}

// ---------------- per-dst-node softmax aggregation ----------------
// One wave per dst node; slot-layout cols: c0=(lane>>4)*32+(lane&15), c1=c0+16.
// Gather loop: unguarded 16-wide batches -- lanes >= m hold sidx=0 (valid row)
// and p=0, so fma(0, h[0], acc) == acc. No serial tail => 16 gathers in flight.
__global__ __launch_bounds__(256)
void k_agg(const uint32* __restrict__ Hh, const float* __restrict__ ssrc,
           const float* __restrict__ sdst, const int* __restrict__ offs,
           const int* __restrict__ csr, const float* __restrict__ bias,
           const float* __restrict__ gam, const float* __restrict__ bet,
           const float* __restrict__ mu, const float* __restrict__ var,
           uint32* __restrict__ Ybf, int n) {
  const int wid = (blockIdx.x * blockDim.x + threadIdx.x) >> 6;
  const int lane = threadIdx.x & 63;
  if (wid >= n) return;
  const int s0 = offs[wid], s1 = offs[wid + 1];
  const float sdv = sdst[wid];
  const int c0 = (lane >> 4) * 32 + (lane & 15);
  const int c1 = c0 + 16;
  float acc0 = 0.f, acc1 = 0.f, denom = 0.f, mx = -1e30f;
  for (int base = s0; base < s1; base += 64) {
    const int m = min(64, s1 - base);
    int sidx = 0;
    float e = -1e30f;
    if (lane < m) {
      sidx = csr[base + lane];
      float tt = ssrc[sidx] + sdv;
      e = (tt > 0.f) ? tt : NEG * tt;
    }
    const float cmx = wave_max_f(e);
    const float nmx = fmaxf(mx, cmx);
    if (nmx > mx) {
      const float sc = __expf(mx - nmx);
      acc0 *= sc; acc1 *= sc; denom *= sc;
      mx = nmx;
    }
    const float p = (lane < m) ? __expf(e - mx) : 0.f;
    denom += wave_sum_f(p);
    const uint32 pu = __float_as_uint(p);
    for (int jj = 0; jj < m; jj += 16) {
      int idxv[16];
      float wv[16];
#pragma unroll
      for (int u = 0; u < 16; ++u) {
        idxv[u] = __builtin_amdgcn_readlane(sidx, jj + u);
        wv[u] = __uint_as_float(__builtin_amdgcn_readlane(pu, jj + u));
      }
      uint32 g[16];
#pragma unroll
      for (int u = 0; u < 16; ++u) g[u] = Hh[(long)idxv[u] * 64 + lane];
#pragma unroll
      for (int u = 0; u < 16; ++u) {
        acc0 = fmaf(wv[u], __uint_as_float(g[u] << 16), acc0);
        acc1 = fmaf(wv[u], __uint_as_float(g[u] & 0xffff0000u), acc1);
      }
    }
  }
  const float inv = 1.f / denom;
  float v0 = acc0 * inv + bias[c0];
  float v1 = acc1 * inv + bias[c1];
  const float sc0 = gam[c0] * rsqrtf(var[c0] + BNEPS);
  const float sc1 = gam[c1] * rsqrtf(var[c1] + BNEPS);
  v0 = fmaxf((v0 - mu[c0]) * sc0 + bet[c0], 0.f);
  v1 = fmaxf((v1 - mu[c1]) * sc1 + bet[c1], 0.f);
  Ybf[(long)wid * 64 + lane] = f2bf(v0) | (f2bf(v1) << 16);
}

// ---------------- global mean pool + MLP head (bf16 Y, slot layout) ----------------
__global__ __launch_bounds__(256)
void k_pool_head(const uint32* __restrict__ Ybf, const int* __restrict__ batch, int n,
                 const float* __restrict__ lw1, const float* __restrict__ lb1,
                 const float* __restrict__ lw2, const float* __restrict__ lb2,
                 float* __restrict__ out) {
  const int g = blockIdx.x;
  const int wave = threadIdx.x >> 6, lane = threadIdx.x & 63;
  int lo = 0, hi = n;
  while (lo < hi) { int mid = (lo + hi) >> 1; if (batch[mid] < g) lo = mid + 1; else hi = mid; }
  const int start = lo;
  hi = n;
  while (lo < hi) { int mid = (lo + hi) >> 1; if (batch[mid] < g + 1) lo = mid + 1; else hi = mid; }
  const int end = lo;
  const int c0 = (lane >> 4) * 32 + (lane & 15);
  const int c1 = c0 + 16;
  float m0 = 0.f, m1 = 0.f;
  for (int i = start + wave; i < end; i += 4) {
    const uint32 gv = Ybf[(long)i * 64 + lane];
    m0 += __uint_as_float(gv << 16);
    m1 += __uint_as_float(gv & 0xffff0000u);
  }
  __shared__ float red[4][HD];
  red[wave][c0] = m0;
  red[wave][c1] = m1;
  __syncthreads();
  if (wave == 0) {
    m0 = red[0][c0] + red[1][c0] + red[2][c0] + red[3][c0];
    m1 = red[0][c1] + red[1][c1] + red[2][c1] + red[3][c1];
    const float cnt = (float)(end - start);
    const float invc = (cnt > 0.f) ? 1.f / cnt : 0.f;
    m0 *= invc;
    m1 *= invc;
    float t0 = lb1[c0], t1 = lb1[c1];
    for (int k = 0; k < HD; ++k) {
      const int srcl = ((k >> 5) << 4) + (k & 15);
      const float pv = __shfl(((k >> 4) & 1) ? m1 : m0, srcl, 64);
      t0 = fmaf(pv, lw1[k * HD + c0], t0);
      t1 = fmaf(pv, lw1[k * HD + c1], t1);
    }
    t0 = fmaxf(t0, 0.f);
    t1 = fmaxf(t1, 0.f);
    float p = t0 * lw2[c0] + t1 * lw2[c1];
#pragma unroll
    for (int off = 32; off; off >>= 1) p += __shfl_xor(p, off, 64);
    if (lane == 0) out[g] = p + lb2[0];
  }
}

// ---------------- launch ----------------

extern "C" void kernel_launch(void* const* d_in, const int* in_sizes, int n_in,
                              void* d_out, int out_size, void* d_ws, size_t ws_size,
                              hipStream_t stream) {
  const float* x = (const float*)d_in[0];
  const int* ei = (const int*)d_in[1];
  const int* batch = (const int*)d_in[2];
  const float* W1 = (const float*)d_in[3];
  const float* as1 = (const float*)d_in[4];
  const float* ad1 = (const float*)d_in[5];
  const float* b1 = (const float*)d_in[6];
  const float* W2 = (const float*)d_in[7];
  const float* as2 = (const float*)d_in[8];
  const float* ad2 = (const float*)d_in[9];
  const float* b2 = (const float*)d_in[10];
  const float* W3 = (const float*)d_in[11];
  const float* as3 = (const float*)d_in[12];
  const float* ad3 = (const float*)d_in[13];
  const float* b3 = (const float*)d_in[14];
  const float* g1 = (const float*)d_in[15];
  const float* be1 = (const float*)d_in[16];
  const float* m1 = (const float*)d_in[17];
  const float* v1 = (const float*)d_in[18];
  const float* g2 = (const float*)d_in[19];
  const float* be2 = (const float*)d_in[20];
  const float* m2 = (const float*)d_in[21];
  const float* v2 = (const float*)d_in[22];
  const float* g3 = (const float*)d_in[23];
  const float* be3 = (const float*)d_in[24];
  const float* m3 = (const float*)d_in[25];
  const float* v3 = (const float*)d_in[26];
  const float* lw1 = (const float*)d_in[27];
  const float* lb1 = (const float*)d_in[28];
  const float* lw2 = (const float*)d_in[29];
  const float* lb2 = (const float*)d_in[30];

  const int n = in_sizes[0] / 64;  // 50000
  const int E = in_sizes[1] / 2;   // 640000
  const int* src = ei;
  const int* dst = ei + E;

  // workspace carve (4B units)
  uint32* hbuf = (uint32*)d_ws;        // n*64 (bf16x2 packed h)
  uint32* ybuf = hbuf + (long)n * 64;  // n*64 (bf16x2 packed y)
  float* ssrc = (float*)(ybuf + (long)n * 64);  // n
  float* sdstv = ssrc + n;             // n
  int* deg = (int*)(sdstv + n);        // n
  int* offs = deg + n;                 // n+1
  int* cursor = offs + n + 1;          // n
  int* csr = cursor + n;               // E+n
  int* part = csr + (E + n);           // <=256
  uint32* PW1 = (uint32*)(part + 256); // 4096
  uint32* PW2 = PW1 + 4096;            // 8192
  uint32* PW3 = PW2 + 8192;            // 8192
  uint32* BFA1 = PW3 + 8192;           // 512
  uint32* BFA2 = BFA1 + 512;           // 1024
  uint32* BFA3 = BFA2 + 1024;          // 1024

  const int B = 256;
  dim3 blk(B);
  const int nb = (n + B - 1) / B;

  // pack everything (PW + score fragments) in one kernel
  k_pack<<<dim3(83), blk, 0, stream>>>(W1, as1, ad1, W2, as2, ad2, W3, as3, ad3,
                                       PW1, PW2, PW3, BFA1, BFA2, BFA3);

  // CSR build (reused by all 3 layers)
  hipMemsetAsync(deg, 0, (size_t)n * sizeof(int), stream);
  k_hist<<<dim3((E + B - 1) / B), blk, 0, stream>>>(dst, deg, E);
  k_scan_part<<<dim3(nb), blk, 0, stream>>>(deg, part, n);
  k_scan_part2<<<dim3(1), blk, 0, stream>>>(part, nb);
  k_scan_final<<<dim3(nb), blk, 0, stream>>>(deg, part, offs, csr, cursor, n);
  k_fill_edges<<<dim3((E + B - 1) / B), blk, 0, stream>>>(src, dst, cursor, csr, E);

  const dim3 ggrid((n + 63) / 64);
  const dim3 agrid((n + 3) / 4);

  // layer 1
  k_gemm_mfma<64, false><<<ggrid, blk, 0, stream>>>(x, PW1, BFA1, hbuf, ssrc, sdstv, n);
  k_agg<<<agrid, blk, 0, stream>>>(hbuf, ssrc, sdstv, offs, csr, b1, g1, be1, m1, v1, ybuf, n);
  // layer 2
  k_gemm_mfma<128, true><<<ggrid, blk, 0, stream>>>(ybuf, PW2, BFA2, hbuf, ssrc, sdstv, n);
  k_agg<<<agrid, blk, 0, stream>>>(hbuf, ssrc, sdstv, offs, csr, b2, g2, be2, m2, v2, ybuf, n);
  // layer 3
  k_gemm_mfma<128, true><<<ggrid, blk, 0, stream>>>(ybuf, PW3, BFA3, hbuf, ssrc, sdstv, n);
  k_agg<<<agrid, blk, 0, stream>>>(hbuf, ssrc, sdstv, offs, csr, b3, g3, be3, m3, v3, ybuf, n);

  // pool + head
  k_pool_head<<<dim3(256), blk, 0, stream>>>(ybuf, batch, n, lw1, lb1, lw2, lb2,
                                             (float*)d_out);
}

// Round 6
// 235.075 us; speedup vs baseline: 2.8856x; 1.0320x over previous
//
#include <hip/hip_runtime.h>

#define HD 128
#define NEG 0.2f
#define BNEPS 1e-5f

typedef unsigned int uint32;
typedef __attribute__((ext_vector_type(8))) short short8;   // 8 bf16 (4 VGPRs)
typedef __attribute__((ext_vector_type(4))) float floatx4;  // MFMA acc

// ---------------- wave helpers ----------------

__device__ inline float wave_sum_f(float v) {
#pragma unroll
  for (int off = 32; off; off >>= 1) v += __shfl_xor(v, off, 64);
  return v;
}
__device__ inline int wave_iscan_i(int v, int lane) {
#pragma unroll
  for (int off = 1; off < 64; off <<= 1) {
    int t = __shfl_up(v, off, 64);
    if (lane >= off) v += t;
  }
  return v;
}
__device__ inline uint32 f2bf(float f) {  // fp32 -> bf16 (RNE), low 16 bits
  uint32 u = __float_as_uint(f);
  return (u + 0x7fffu + ((u >> 16) & 1u)) >> 16;
}
// fragment k-pair for B-side packing. perm=false: linear k (fp32-staged A).
// perm=true: A comes from slot-layout bf16 Y; word w holds cols (q, q+16),
// q = (w>>4)*32 + (w&15); fragment word w = kc*16 + lg*4 + e2.
__device__ inline void kpair(int kc, int lg, int e2, bool perm, int& k_lo, int& k_hi) {
  if (!perm) {
    k_lo = kc * 32 + lg * 8 + e2 * 2;
    k_hi = k_lo + 1;
  } else {
    int w = kc * 16 + lg * 4 + e2;
    k_lo = ((w >> 4) << 5) + (w & 15);
    k_hi = k_lo + 16;
  }
}

// ---------------- combined pack + deg/gcnt zero ----------------
// blocks 0..15: PW1 (K=64, linear); 16..47: PW2 (perm); 48..79: PW3 (perm);
// 80..82: score B-fragments (col0 = W@a_s, col1 = W@a_d); 83..: zero deg (+gcnt).
__global__ __launch_bounds__(256)
void k_pack(const float* __restrict__ W1, const float* __restrict__ as1v,
            const float* __restrict__ ad1v, const float* __restrict__ W2,
            const float* __restrict__ as2v, const float* __restrict__ ad2v,
            const float* __restrict__ W3, const float* __restrict__ as3v,
            const float* __restrict__ ad3v, uint32* __restrict__ PW1,
            uint32* __restrict__ PW2, uint32* __restrict__ PW3,
            uint32* __restrict__ BFA1, uint32* __restrict__ BFA2,
            uint32* __restrict__ BFA3, int* __restrict__ deg,
            int* __restrict__ gcnt, int n) {
  const int b = blockIdx.x, t = threadIdx.x;
  if (b >= 83) {
    const int i = (b - 83) * 256 + t;
    if (i < n) deg[i] = 0;
    if (b == 83 && t == 0) gcnt[0] = 0;
    return;
  }
  if (b < 80) {
    const float* W;
    uint32* PW;
    int KC, local;
    bool perm;
    if (b < 16) { W = W1; PW = PW1; KC = 2; perm = false; local = b; }
    else if (b < 48) { W = W2; PW = PW2; KC = 4; perm = true; local = b - 16; }
    else { W = W3; PW = PW3; KC = 4; perm = true; local = b - 48; }
    const int idx = local * 256 + t;
    const int e2 = idx & 3, l = (idx >> 2) & 63, f = idx >> 8;
    const int kc = f % KC, ct = f / KC;
    int k_lo, k_hi;
    kpair(kc, l >> 4, e2, perm, k_lo, k_hi);
    const int col = ct * 16 + (l & 15);
    PW[idx] = f2bf(W[k_lo * HD + col]) | (f2bf(W[k_hi * HD + col]) << 16);
  } else {
    const int layer = b - 80;
    const float* W = layer == 0 ? W1 : layer == 1 ? W2 : W3;
    const float* av = layer == 0 ? as1v : layer == 1 ? as2v : as3v;
    const float* dv = layer == 0 ? ad1v : layer == 1 ? ad2v : ad3v;
    uint32* BFA = layer == 0 ? BFA1 : layer == 1 ? BFA2 : BFA3;
    const int K = layer == 0 ? 64 : 128, KC = K / 32;
    const bool perm = layer != 0;
    __shared__ float ws[128], wd[128];
    if (t < K) {
      float s = 0.f, d = 0.f;
      for (int j = 0; j < HD; ++j) {
        const float w = W[t * HD + j];
        s = fmaf(w, av[j], s);
        d = fmaf(w, dv[j], d);
      }
      ws[t] = s;
      wd[t] = d;
    }
    __syncthreads();
    const int total = KC * 256;  // KC*64*4 uint32 words
    for (int idx = t; idx < total; idx += 256) {
      const int e2 = idx & 3, l = (idx >> 2) & 63, kc = idx >> 8;
      int k_lo, k_hi;
      kpair(kc, l >> 4, e2, perm, k_lo, k_hi);
      const int li = l & 15;
      const float lo = li == 0 ? ws[k_lo] : li == 1 ? wd[k_lo] : 0.f;
      const float hi = li == 0 ? ws[k_hi] : li == 1 ? wd[k_hi] : 0.f;
      BFA[idx] = f2bf(lo) | (f2bf(hi) << 16);
    }
  }
}

// ---------------- CSR: atomic segment allocation (scan-free) ----------------
// Segment placement is run-varying (atomic block order) but contents/values are
// not: agg only reads [start, start+deg+1) which always holds {self, edges}.
__global__ __launch_bounds__(256)
void k_alloc(const int* __restrict__ deg, int* __restrict__ gcnt,
             int2* __restrict__ offs2, int* __restrict__ csr,
             int* __restrict__ cursor, int n) {
  const int t = threadIdx.x, lane = t & 63, wave = t >> 6;
  const int i = blockIdx.x * 256 + t;
  const int v = (i < n) ? deg[i] + 1 : 0;
  const int x = wave_iscan_i(v, lane);  // inclusive wave scan
  __shared__ int wsum[4];
  __shared__ int bbase;
  if (lane == 63) wsum[wave] = x;
  __syncthreads();
  if (t == 0) bbase = atomicAdd(gcnt, wsum[0] + wsum[1] + wsum[2] + wsum[3]);
  __syncthreads();
  int add = bbase;
#pragma unroll
  for (int w = 0; w < 4; ++w)
    if (w < wave) add += wsum[w];
  const int start = add + x - v;  // exclusive prefix within allocation
  if (i < n) {
    offs2[i] = make_int2(start, start + v);
    csr[start] = i;  // self-loop first
    cursor[i] = start + 1;
  }
}

__global__ void k_fill_edges(const int* __restrict__ src, const int* __restrict__ dst,
                             int* __restrict__ cursor, int* __restrict__ csr, int E) {
  int i = blockIdx.x * blockDim.x + threadIdx.x;
  if (i < E) { int p = atomicAdd(&cursor[dst[i]], 1); csr[p] = src[i]; }
}

// ---------------- MFMA GEMM body ----------------
// h = X @ W via mfma_f32_16x16x32_bf16. 64 rows/block; 4 waves split 128 cols.
// Scores via wave-0 MFMA against BFA (cols 0/1 = W@a_s, W@a_d).
// Hh written packed bf16x2 slot layout: word w = wv*16+(l&15) holds cols (q, q+16),
// q = (w>>4)*32 + (w&15).
template <int K, bool BF16IN>
__device__ inline void gemm_body(int bid, const void* __restrict__ Xv,
                                 const uint32* __restrict__ PW,
                                 const uint32* __restrict__ BFA,
                                 uint32* __restrict__ Hh, float* __restrict__ ssrc,
                                 float* __restrict__ sdst, int n) {
  constexpr int KC = K / 32;
  __shared__ uint32 Xl[64 * K / 2];
  const int t = threadIdx.x;
  const int wv = t >> 6, l = t & 63;
  const int rowbase = bid * 64;

  // B fragments -> registers
  short8 bfr[2][KC];
#pragma unroll
  for (int c2 = 0; c2 < 2; ++c2)
#pragma unroll
    for (int kc = 0; kc < KC; ++kc)
      bfr[c2][kc] = *((const short8*)PW + ((wv * 2 + c2) * KC + kc) * 64 + l);
  short8 bfa[KC];
  if (wv == 0) {
#pragma unroll
    for (int kc = 0; kc < KC; ++kc) bfa[kc] = *((const short8*)BFA + kc * 64 + l);
  }

  // stage X -> LDS (bf16, XOR-swizzled: byte ^ ((row&7)<<4))
  if (BF16IN) {
    const uint32* Xb = (const uint32*)Xv;
#pragma unroll
    for (int B = t; B < 64 * (K / 8); B += 256) {
      const int row = B / (K / 8), cb = B % (K / 8);
      const int r = min(rowbase + row, n - 1);
      const uint4 v = *(const uint4*)&Xb[(long)r * (K / 2) + cb * 4];
      *(uint4*)&Xl[row * (K / 2) + (cb ^ (row & 7)) * 4] = v;
    }
  } else {
    const float* X = (const float*)Xv;
    for (int i = t; i < 64 * (K / 4); i += 256) {
      const int row = i / (K / 4), kq = i % (K / 4);
      const int r = min(rowbase + row, n - 1);
      const float4 v = *(const float4*)&X[(long)r * K + kq * 4];
      uint2 p;
      p.x = f2bf(v.x) | (f2bf(v.y) << 16);
      p.y = f2bf(v.z) | (f2bf(v.w) << 16);
      int byte = row * (K * 2) + kq * 8;
      byte ^= (row & 7) << 4;
      *(uint2*)((char*)Xl + byte) = p;
    }
  }
  __syncthreads();

  floatx4 acc[4][2], acc2[4];
#pragma unroll
  for (int rt = 0; rt < 4; ++rt) {
    acc[rt][0] = (floatx4){0.f, 0.f, 0.f, 0.f};
    acc[rt][1] = (floatx4){0.f, 0.f, 0.f, 0.f};
    acc2[rt] = (floatx4){0.f, 0.f, 0.f, 0.f};
  }
  const int row_l = l & 15, kgrp = l >> 4;
#pragma unroll
  for (int rt = 0; rt < 4; ++rt) {
    const int row = rt * 16 + row_l;
#pragma unroll
    for (int kc = 0; kc < KC; ++kc) {
      const int byte = (row * (K * 2) + kc * 64 + kgrp * 16) ^ ((row & 7) << 4);
      const short8 af = *(const short8*)((const char*)Xl + byte);
      acc[rt][0] = __builtin_amdgcn_mfma_f32_16x16x32_bf16(af, bfr[0][kc], acc[rt][0], 0, 0, 0);
      acc[rt][1] = __builtin_amdgcn_mfma_f32_16x16x32_bf16(af, bfr[1][kc], acc[rt][1], 0, 0, 0);
      if (wv == 0)
        acc2[rt] = __builtin_amdgcn_mfma_f32_16x16x32_bf16(af, bfa[kc], acc2[rt], 0, 0, 0);
    }
  }

  // epilogue: packed bf16 h store + direct score stores (wave 0, cols 0/1)
#pragma unroll
  for (int rt = 0; rt < 4; ++rt) {
#pragma unroll
    for (int r = 0; r < 4; ++r) {
      const int R = rowbase + rt * 16 + kgrp * 4 + r;
      if (R < n)
        Hh[(long)R * 64 + wv * 16 + row_l] =
            f2bf(acc[rt][0][r]) | (f2bf(acc[rt][1][r]) << 16);
    }
  }
  if (wv == 0 && row_l < 2) {
    float* tgt = (row_l == 0) ? ssrc : sdst;
#pragma unroll
    for (int rt = 0; rt < 4; ++rt)
#pragma unroll
      for (int r = 0; r < 4; ++r) {
        const int R = rowbase + rt * 16 + kgrp * 4 + r;
        if (R < n) tgt[R] = acc2[rt][r];
      }
  }
}

// layer-1 gemm (fp32 in, K=64) fused with edge histogram: blocks [0,GB) gemm,
// blocks [GB, GB+E/256) histogram (both depend only on k_pack outputs).
__global__ __launch_bounds__(256)
void k_gemm1_hist(const void* __restrict__ Xv, const uint32* __restrict__ PW,
                  const uint32* __restrict__ BFA, uint32* __restrict__ Hh,
                  float* __restrict__ ssrc, float* __restrict__ sdst, int n,
                  const int* __restrict__ dst, int* __restrict__ deg, int E, int GB) {
  const int b = blockIdx.x;
  if (b < GB) {
    gemm_body<64, false>(b, Xv, PW, BFA, Hh, ssrc, sdst, n);
  } else {
    const int i = (b - GB) * 256 + threadIdx.x;
    if (i < E) atomicAdd(&deg[dst[i]], 1);
  }
}

template <int K>
__global__ __launch_bounds__(256)
void k_gemm_mfma(const void* __restrict__ Xv, const uint32* __restrict__ PW,
                 const uint32* __restrict__ BFA, uint32* __restrict__ Hh,
                 float* __restrict__ ssrc, float* __restrict__ sdst, int n) {
  gemm_body<K, true>(blockIdx.x, Xv, PW, BFA, Hh, ssrc, sdst, n);
}

// ---------------- per-dst-node softmax aggregation ----------------
// One wave per dst node; slot cols: c0=(lane>>4)*32+(lane&15), c1=c0+16.
// No max-subtraction (scores bounded, exp safe in fp32 -- matches reference to
// rounding). Guarded 16-wide gather batches; indices/weights via readlane (SGPR).
__global__ __launch_bounds__(256)
void k_agg(const uint32* __restrict__ Hh, const float* __restrict__ ssrc,
           const float* __restrict__ sdst, const int2* __restrict__ offs2,
           const int* __restrict__ csr, const float* __restrict__ bias,
           const float* __restrict__ gam, const float* __restrict__ bet,
           const float* __restrict__ mu, const float* __restrict__ var,
           uint32* __restrict__ Ybf, int n) {
  const int wid = (blockIdx.x * blockDim.x + threadIdx.x) >> 6;
  const int lane = threadIdx.x & 63;
  if (wid >= n) return;
  const int2 se = offs2[wid];
  const float sdv = sdst[wid];
  const int c0 = (lane >> 4) * 32 + (lane & 15);
  const int c1 = c0 + 16;
  float acc0 = 0.f, acc1 = 0.f, denom = 0.f;
  for (int base = se.x; base < se.y; base += 64) {
    const int m = min(64, se.y - base);
    int sidx = 0;
    float p = 0.f;
    if (lane < m) {
      sidx = csr[base + lane];
      const float tt = ssrc[sidx] + sdv;
      const float e = (tt > 0.f) ? tt : NEG * tt;
      p = __expf(e);
    }
    denom += wave_sum_f(p);
    const uint32 pu = __float_as_uint(p);
    for (int jj = 0; jj < m; jj += 16) {
      uint32 g[16];
#pragma unroll
      for (int u = 0; u < 16; ++u) {
        if (jj + u < m) {
          const int s = __builtin_amdgcn_readlane(sidx, jj + u);
          g[u] = Hh[(long)s * 64 + lane];
        }
      }
#pragma unroll
      for (int u = 0; u < 16; ++u) {
        if (jj + u < m) {
          const float w = __uint_as_float(__builtin_amdgcn_readlane(pu, jj + u));
          acc0 = fmaf(w, __uint_as_float(g[u] << 16), acc0);
          acc1 = fmaf(w, __uint_as_float(g[u] & 0xffff0000u), acc1);
        }
      }
    }
  }
  const float inv = 1.f / denom;
  float v0 = acc0 * inv + bias[c0];
  float v1 = acc1 * inv + bias[c1];
  const float sc0 = gam[c0] * rsqrtf(var[c0] + BNEPS);
  const float sc1 = gam[c1] * rsqrtf(var[c1] + BNEPS);
  v0 = fmaxf((v0 - mu[c0]) * sc0 + bet[c0], 0.f);
  v1 = fmaxf((v1 - mu[c1]) * sc1 + bet[c1], 0.f);
  Ybf[(long)wid * 64 + lane] = f2bf(v0) | (f2bf(v1) << 16);
}

// ---------------- global mean pool + MLP head (bf16 Y, slot layout) ----------------
__global__ __launch_bounds__(256)
void k_pool_head(const uint32* __restrict__ Ybf, const int* __restrict__ batch, int n,
                 const float* __restrict__ lw1, const float* __restrict__ lb1,
                 const float* __restrict__ lw2, const float* __restrict__ lb2,
                 float* __restrict__ out) {
  const int g = blockIdx.x;
  const int wave = threadIdx.x >> 6, lane = threadIdx.x & 63;
  int lo = 0, hi = n;
  while (lo < hi) { int mid = (lo + hi) >> 1; if (batch[mid] < g) lo = mid + 1; else hi = mid; }
  const int start = lo;
  hi = n;
  while (lo < hi) { int mid = (lo + hi) >> 1; if (batch[mid] < g + 1) lo = mid + 1; else hi = mid; }
  const int end = lo;
  const int c0 = (lane >> 4) * 32 + (lane & 15);
  const int c1 = c0 + 16;
  float m0 = 0.f, m1 = 0.f;
  for (int i = start + wave; i < end; i += 4) {
    const uint32 gv = Ybf[(long)i * 64 + lane];
    m0 += __uint_as_float(gv << 16);
    m1 += __uint_as_float(gv & 0xffff0000u);
  }
  __shared__ float red[4][HD];
  red[wave][c0] = m0;
  red[wave][c1] = m1;
  __syncthreads();
  if (wave == 0) {
    m0 = red[0][c0] + red[1][c0] + red[2][c0] + red[3][c0];
    m1 = red[0][c1] + red[1][c1] + red[2][c1] + red[3][c1];
    const float cnt = (float)(end - start);
    const float invc = (cnt > 0.f) ? 1.f / cnt : 0.f;
    m0 *= invc;
    m1 *= invc;
    float t0 = lb1[c0], t1 = lb1[c1];
    for (int k = 0; k < HD; ++k) {
      const int srcl = ((k >> 5) << 4) + (k & 15);
      const float pv = __shfl(((k >> 4) & 1) ? m1 : m0, srcl, 64);
      t0 = fmaf(pv, lw1[k * HD + c0], t0);
      t1 = fmaf(pv, lw1[k * HD + c1], t1);
    }
    t0 = fmaxf(t0, 0.f);
    t1 = fmaxf(t1, 0.f);
    float p = t0 * lw2[c0] + t1 * lw2[c1];
#pragma unroll
    for (int off = 32; off; off >>= 1) p += __shfl_xor(p, off, 64);
    if (lane == 0) out[g] = p + lb2[0];
  }
}

// ---------------- launch ----------------

extern "C" void kernel_launch(void* const* d_in, const int* in_sizes, int n_in,
                              void* d_out, int out_size, void* d_ws, size_t ws_size,
                              hipStream_t stream) {
  const float* x = (const float*)d_in[0];
  const int* ei = (const int*)d_in[1];
  const int* batch = (const int*)d_in[2];
  const float* W1 = (const float*)d_in[3];
  const float* as1 = (const float*)d_in[4];
  const float* ad1 = (const float*)d_in[5];
  const float* b1 = (const float*)d_in[6];
  const float* W2 = (const float*)d_in[7];
  const float* as2 = (const float*)d_in[8];
  const float* ad2 = (const float*)d_in[9];
  const float* b2 = (const float*)d_in[10];
  const float* W3 = (const float*)d_in[11];
  const float* as3 = (const float*)d_in[12];
  const float* ad3 = (const float*)d_in[13];
  const float* b3 = (const float*)d_in[14];
  const float* g1 = (const float*)d_in[15];
  const float* be1 = (const float*)d_in[16];
  const float* m1 = (const float*)d_in[17];
  const float* v1 = (const float*)d_in[18];
  const float* g2 = (const float*)d_in[19];
  const float* be2 = (const float*)d_in[20];
  const float* m2 = (const float*)d_in[21];
  const float* v2 = (const float*)d_in[22];
  const float* g3 = (const float*)d_in[23];
  const float* be3 = (const float*)d_in[24];
  const float* m3 = (const float*)d_in[25];
  const float* v3 = (const float*)d_in[26];
  const float* lw1 = (const float*)d_in[27];
  const float* lb1 = (const float*)d_in[28];
  const float* lw2 = (const float*)d_in[29];
  const float* lb2 = (const float*)d_in[30];

  const int n = in_sizes[0] / 64;  // 50000
  const int E = in_sizes[1] / 2;   // 640000
  const int* src = ei;
  const int* dst = ei + E;

  // workspace carve (4B units; offs2 offset is 8B-aligned by construction)
  uint32* hbuf = (uint32*)d_ws;        // n*64 (bf16x2 packed h)
  uint32* ybuf = hbuf + (long)n * 64;  // n*64 (bf16x2 packed y)
  float* ssrc = (float*)(ybuf + (long)n * 64);  // n
  float* sdstv = ssrc + n;             // n
  int* deg = (int*)(sdstv + n);        // n
  int2* offs2 = (int2*)(deg + n);      // n int2
  int* cursor = (int*)(offs2 + n);     // n
  int* csr = cursor + n;               // E+n
  int* gcnt = csr + (E + n);           // 1 (+pad)
  uint32* PW1 = (uint32*)(gcnt + 4);   // 4096
  uint32* PW2 = PW1 + 4096;            // 8192
  uint32* PW3 = PW2 + 8192;            // 8192
  uint32* BFA1 = PW3 + 8192;           // 512
  uint32* BFA2 = BFA1 + 512;           // 1024
  uint32* BFA3 = BFA2 + 1024;          // 1024

  const int B = 256;
  dim3 blk(B);
  const int nb = (n + B - 1) / B;      // 196
  const int eb = (E + B - 1) / B;      // 2500
  const int GB = (n + 63) / 64;        // 782 gemm blocks

  // 1: pack (PW + score fragments) + zero deg/gcnt
  k_pack<<<dim3(83 + nb), blk, 0, stream>>>(W1, as1, ad1, W2, as2, ad2, W3, as3, ad3,
                                            PW1, PW2, PW3, BFA1, BFA2, BFA3,
                                            deg, gcnt, n);
  // 2: layer-1 gemm (fp32 in) || edge histogram
  k_gemm1_hist<<<dim3(GB + eb), blk, 0, stream>>>(x, PW1, BFA1, hbuf, ssrc, sdstv, n,
                                                  dst, deg, E, GB);
  // 3: CSR segment allocation (scan-free)
  k_alloc<<<dim3(nb), blk, 0, stream>>>(deg, gcnt, offs2, csr, cursor, n);
  // 4: CSR edge fill
  k_fill_edges<<<dim3(eb), blk, 0, stream>>>(src, dst, cursor, csr, E);

  const dim3 agrid((n + 3) / 4);
  // 5: agg layer 1
  k_agg<<<agrid, blk, 0, stream>>>(hbuf, ssrc, sdstv, offs2, csr, b1, g1, be1, m1, v1, ybuf, n);
  // 6-7: layer 2
  k_gemm_mfma<128><<<dim3(GB), blk, 0, stream>>>(ybuf, PW2, BFA2, hbuf, ssrc, sdstv, n);
  k_agg<<<agrid, blk, 0, stream>>>(hbuf, ssrc, sdstv, offs2, csr, b2, g2, be2, m2, v2, ybuf, n);
  // 8-9: layer 3
  k_gemm_mfma<128><<<dim3(GB), blk, 0, stream>>>(ybuf, PW3, BFA3, hbuf, ssrc, sdstv, n);
  k_agg<<<agrid, blk, 0, stream>>>(hbuf, ssrc, sdstv, offs2, csr, b3, g3, be3, m3, v3, ybuf, n);
  // 10: pool + head
  k_pool_head<<<dim3(256), blk, 0, stream>>>(ybuf, batch, n, lw1, lb1, lw2, lb2,
                                             (float*)d_out);
}

// Round 7
// 229.277 us; speedup vs baseline: 2.9586x; 1.0253x over previous
//
#include <hip/hip_runtime.h>

#define HD 128
#define NEG 0.2f
#define BNEPS 1e-5f
#define BSH 11          // src bucket = src >> 11  (25 buckets for n=50000)
#define NBSLOT 32       // padded bucket slots per node

typedef unsigned int uint32;
typedef __attribute__((ext_vector_type(8))) short short8;   // 8 bf16 (4 VGPRs)
typedef __attribute__((ext_vector_type(4))) float floatx4;  // MFMA acc

// ---------------- wave helpers ----------------

__device__ inline float wave_sum_f(float v) {
#pragma unroll
  for (int off = 32; off; off >>= 1) v += __shfl_xor(v, off, 64);
  return v;
}
__device__ inline int wave_iscan_i(int v, int lane) {
#pragma unroll
  for (int off = 1; off < 64; off <<= 1) {
    int t = __shfl_up(v, off, 64);
    if (lane >= off) v += t;
  }
  return v;
}
__device__ inline uint32 f2bf(float f) {  // fp32 -> bf16 (RNE), low 16 bits
  uint32 u = __float_as_uint(f);
  return (u + 0x7fffu + ((u >> 16) & 1u)) >> 16;
}
// fragment k-pair for B-side packing. perm=false: linear k (fp32-staged A).
// perm=true: A comes from slot-layout bf16 Y; word w holds cols (q, q+16),
// q = (w>>4)*32 + (w&15); fragment word w = kc*16 + lg*4 + e2.
__device__ inline void kpair(int kc, int lg, int e2, bool perm, int& k_lo, int& k_hi) {
  if (!perm) {
    k_lo = kc * 32 + lg * 8 + e2 * 2;
    k_hi = k_lo + 1;
  } else {
    int w = kc * 16 + lg * 4 + e2;
    k_lo = ((w >> 4) << 5) + (w & 15);
    k_hi = k_lo + 16;
  }
}

// ---------------- combined pack + zero ----------------
// blocks 0..15: PW1; 16..47: PW2; 48..79: PW3; 80..82: BFA + BN(A,B) per layer;
// 83..: zero deg32 (+gcnt).
__global__ __launch_bounds__(256)
void k_pack(const float* __restrict__ W1, const float* __restrict__ as1v,
            const float* __restrict__ ad1v, const float* __restrict__ W2,
            const float* __restrict__ as2v, const float* __restrict__ ad2v,
            const float* __restrict__ W3, const float* __restrict__ as3v,
            const float* __restrict__ ad3v,
            const float* __restrict__ b1, const float* __restrict__ g1,
            const float* __restrict__ be1, const float* __restrict__ m1,
            const float* __restrict__ v1,
            const float* __restrict__ b2, const float* __restrict__ g2,
            const float* __restrict__ be2, const float* __restrict__ m2,
            const float* __restrict__ v2,
            const float* __restrict__ b3, const float* __restrict__ g3,
            const float* __restrict__ be3, const float* __restrict__ m3,
            const float* __restrict__ v3,
            uint32* __restrict__ PW1, uint32* __restrict__ PW2,
            uint32* __restrict__ PW3, uint32* __restrict__ BFA1,
            uint32* __restrict__ BFA2, uint32* __restrict__ BFA3,
            float4* __restrict__ BNAB,  // [3][64] (A_c0,B_c0,A_c1,B_c1)
            int* __restrict__ deg32, int* __restrict__ gcnt, int n) {
  const int b = blockIdx.x, t = threadIdx.x;
  if (b >= 83) {
    const int i = (b - 83) * 256 + t;
    if (i < n * NBSLOT) deg32[i] = 0;
    if (b == 83 && t == 0) gcnt[0] = 0;
    return;
  }
  if (b < 80) {
    const float* W;
    uint32* PW;
    int KC, local;
    bool perm;
    if (b < 16) { W = W1; PW = PW1; KC = 2; perm = false; local = b; }
    else if (b < 48) { W = W2; PW = PW2; KC = 4; perm = true; local = b - 16; }
    else { W = W3; PW = PW3; KC = 4; perm = true; local = b - 48; }
    const int idx = local * 256 + t;
    const int e2 = idx & 3, l = (idx >> 2) & 63, f = idx >> 8;
    const int kc = f % KC, ct = f / KC;
    int k_lo, k_hi;
    kpair(kc, l >> 4, e2, perm, k_lo, k_hi);
    const int col = ct * 16 + (l & 15);
    PW[idx] = f2bf(W[k_lo * HD + col]) | (f2bf(W[k_hi * HD + col]) << 16);
  } else {
    const int layer = b - 80;
    const float* W = layer == 0 ? W1 : layer == 1 ? W2 : W3;
    const float* av = layer == 0 ? as1v : layer == 1 ? as2v : as3v;
    const float* dv = layer == 0 ? ad1v : layer == 1 ? ad2v : ad3v;
    const float* bb = layer == 0 ? b1 : layer == 1 ? b2 : b3;
    const float* gg = layer == 0 ? g1 : layer == 1 ? g2 : g3;
    const float* bt = layer == 0 ? be1 : layer == 1 ? be2 : be3;
    const float* mm = layer == 0 ? m1 : layer == 1 ? m2 : m3;
    const float* vv = layer == 0 ? v1 : layer == 1 ? v2 : v3;
    uint32* BFA = layer == 0 ? BFA1 : layer == 1 ? BFA2 : BFA3;
    const int K = layer == 0 ? 64 : 128, KC = K / 32;
    const bool perm = layer != 0;
    __shared__ float ws[128], wd[128];
    if (t < K) {
      float s = 0.f, d = 0.f;
      for (int j = 0; j < HD; ++j) {
        const float w = W[t * HD + j];
        s = fmaf(w, av[j], s);
        d = fmaf(w, dv[j], d);
      }
      ws[t] = s;
      wd[t] = d;
    }
    __syncthreads();
    const int total = KC * 256;  // KC*64*4 uint32 words
    for (int idx = t; idx < total; idx += 256) {
      const int e2 = idx & 3, l = (idx >> 2) & 63, kc = idx >> 8;
      int k_lo, k_hi;
      kpair(kc, l >> 4, e2, perm, k_lo, k_hi);
      const int li = l & 15;
      const float lo = li == 0 ? ws[k_lo] : li == 1 ? wd[k_lo] : 0.f;
      const float hi = li == 0 ? ws[k_hi] : li == 1 ? wd[k_hi] : 0.f;
      BFA[idx] = f2bf(lo) | (f2bf(hi) << 16);
    }
    // BN fold: per slot word w: cols c0,c1. y = (acc*inv + bias - mu)*A' + beta
    // => A = gam*rsqrt(var+eps); B = (bias - mu)*A + beta.
    if (t < 64) {
      const int c0 = (t >> 4) * 32 + (t & 15);
      const int c1 = c0 + 16;
      const float A0 = gg[c0] * rsqrtf(vv[c0] + BNEPS);
      const float A1 = gg[c1] * rsqrtf(vv[c1] + BNEPS);
      float4 r;
      r.x = A0;
      r.y = (bb[c0] - mm[c0]) * A0 + bt[c0];
      r.z = A1;
      r.w = (bb[c1] - mm[c1]) * A1 + bt[c1];
      BNAB[layer * 64 + t] = r;
    }
  }
}

// ---------------- CSR: bucketed atomic segment allocation ----------------
// One thread per node: sum 32 bucket counts (unused slots are 0), wave-scan +
// one atomicAdd per block for placement, write per-bucket cursors.
__global__ __launch_bounds__(256)
void k_alloc(const int4* __restrict__ deg4, int* __restrict__ gcnt,
             int2* __restrict__ offs2, int* __restrict__ csr,
             int4* __restrict__ cursor4, int n) {
  const int t = threadIdx.x, lane = t & 63, wave = t >> 6;
  const int i = blockIdx.x * 256 + t;
  int4 q[8];
  int tot = 1;  // self-loop
  if (i < n) {
#pragma unroll
    for (int u = 0; u < 8; ++u) {
      q[u] = deg4[i * 8 + u];
      tot += q[u].x + q[u].y + q[u].z + q[u].w;
    }
  } else {
    tot = 0;
  }
  const int x = wave_iscan_i(tot, lane);  // inclusive wave scan
  __shared__ int wsum[4];
  __shared__ int bbase;
  if (lane == 63) wsum[wave] = x;
  __syncthreads();
  if (t == 0) bbase = atomicAdd(gcnt, wsum[0] + wsum[1] + wsum[2] + wsum[3]);
  __syncthreads();
  int add = bbase;
#pragma unroll
  for (int w = 0; w < 4; ++w)
    if (w < wave) add += wsum[w];
  const int start = add + x - tot;
  if (i < n) {
    csr[start] = i;  // self-loop first
    int r = start + 1;
#pragma unroll
    for (int u = 0; u < 8; ++u) {
      int4 c;
      c.x = r; r += q[u].x;
      c.y = r; r += q[u].y;
      c.z = r; r += q[u].z;
      c.w = r; r += q[u].w;
      cursor4[i * 8 + u] = c;
    }
    offs2[i] = make_int2(start, r);
  }
}

__global__ void k_fill_edges(const int* __restrict__ src, const int* __restrict__ dst,
                             int* __restrict__ cursor, int* __restrict__ csr, int E) {
  int i = blockIdx.x * blockDim.x + threadIdx.x;
  if (i < E) {
    const int s = src[i];
    const int p = atomicAdd(&cursor[dst[i] * NBSLOT + (s >> BSH)], 1);
    csr[p] = s;
  }
}

// ---------------- MFMA GEMM body ----------------
// h = X @ W via mfma_f32_16x16x32_bf16. 64 rows/block; 4 waves split 128 cols.
// Scores via wave-0 MFMA against BFA (cols 0/1 = W@a_s, W@a_d).
// Hh packed bf16x2 slot layout: word w = wv*16+(l&15) holds cols (q, q+16),
// q = (w>>4)*32 + (w&15).
template <int K, bool BF16IN>
__device__ inline void gemm_body(int bid, const void* __restrict__ Xv,
                                 const uint32* __restrict__ PW,
                                 const uint32* __restrict__ BFA,
                                 uint32* __restrict__ Hh, float* __restrict__ ssrc,
                                 float* __restrict__ sdst, int n) {
  constexpr int KC = K / 32;
  __shared__ uint32 Xl[64 * K / 2];
  const int t = threadIdx.x;
  const int wv = t >> 6, l = t & 63;
  const int rowbase = bid * 64;

  short8 bfr[2][KC];
#pragma unroll
  for (int c2 = 0; c2 < 2; ++c2)
#pragma unroll
    for (int kc = 0; kc < KC; ++kc)
      bfr[c2][kc] = *((const short8*)PW + ((wv * 2 + c2) * KC + kc) * 64 + l);
  short8 bfa[KC];
  if (wv == 0) {
#pragma unroll
    for (int kc = 0; kc < KC; ++kc) bfa[kc] = *((const short8*)BFA + kc * 64 + l);
  }

  if (BF16IN) {
    const uint32* Xb = (const uint32*)Xv;
#pragma unroll
    for (int B = t; B < 64 * (K / 8); B += 256) {
      const int row = B / (K / 8), cb = B % (K / 8);
      const int r = min(rowbase + row, n - 1);
      const uint4 v = *(const uint4*)&Xb[(long)r * (K / 2) + cb * 4];
      *(uint4*)&Xl[row * (K / 2) + (cb ^ (row & 7)) * 4] = v;
    }
  } else {
    const float* X = (const float*)Xv;
    for (int i = t; i < 64 * (K / 4); i += 256) {
      const int row = i / (K / 4), kq = i % (K / 4);
      const int r = min(rowbase + row, n - 1);
      const float4 v = *(const float4*)&X[(long)r * K + kq * 4];
      uint2 p;
      p.x = f2bf(v.x) | (f2bf(v.y) << 16);
      p.y = f2bf(v.z) | (f2bf(v.w) << 16);
      int byte = row * (K * 2) + kq * 8;
      byte ^= (row & 7) << 4;
      *(uint2*)((char*)Xl + byte) = p;
    }
  }
  __syncthreads();

  floatx4 acc[4][2], acc2[4];
#pragma unroll
  for (int rt = 0; rt < 4; ++rt) {
    acc[rt][0] = (floatx4){0.f, 0.f, 0.f, 0.f};
    acc[rt][1] = (floatx4){0.f, 0.f, 0.f, 0.f};
    acc2[rt] = (floatx4){0.f, 0.f, 0.f, 0.f};
  }
  const int row_l = l & 15, kgrp = l >> 4;
#pragma unroll
  for (int rt = 0; rt < 4; ++rt) {
    const int row = rt * 16 + row_l;
#pragma unroll
    for (int kc = 0; kc < KC; ++kc) {
      const int byte = (row * (K * 2) + kc * 64 + kgrp * 16) ^ ((row & 7) << 4);
      const short8 af = *(const short8*)((const char*)Xl + byte);
      acc[rt][0] = __builtin_amdgcn_mfma_f32_16x16x32_bf16(af, bfr[0][kc], acc[rt][0], 0, 0, 0);
      acc[rt][1] = __builtin_amdgcn_mfma_f32_16x16x32_bf16(af, bfr[1][kc], acc[rt][1], 0, 0, 0);
      if (wv == 0)
        acc2[rt] = __builtin_amdgcn_mfma_f32_16x16x32_bf16(af, bfa[kc], acc2[rt], 0, 0, 0);
    }
  }

#pragma unroll
  for (int rt = 0; rt < 4; ++rt) {
#pragma unroll
    for (int r = 0; r < 4; ++r) {
      const int R = rowbase + rt * 16 + kgrp * 4 + r;
      if (R < n)
        Hh[(long)R * 64 + wv * 16 + row_l] =
            f2bf(acc[rt][0][r]) | (f2bf(acc[rt][1][r]) << 16);
    }
  }
  if (wv == 0 && row_l < 2) {
    float* tgt = (row_l == 0) ? ssrc : sdst;
#pragma unroll
    for (int rt = 0; rt < 4; ++rt)
#pragma unroll
      for (int r = 0; r < 4; ++r) {
        const int R = rowbase + rt * 16 + kgrp * 4 + r;
        if (R < n) tgt[R] = acc2[rt][r];
      }
  }
}

// layer-1 gemm (fp32 in, K=64) fused with bucketed edge histogram.
__global__ __launch_bounds__(256)
void k_gemm1_hist(const void* __restrict__ Xv, const uint32* __restrict__ PW,
                  const uint32* __restrict__ BFA, uint32* __restrict__ Hh,
                  float* __restrict__ ssrc, float* __restrict__ sdst, int n,
                  const int* __restrict__ src, const int* __restrict__ dst,
                  int* __restrict__ deg32, int E, int GB) {
  const int b = blockIdx.x;
  if (b < GB) {
    gemm_body<64, false>(b, Xv, PW, BFA, Hh, ssrc, sdst, n);
  } else {
    const int i = (b - GB) * 256 + threadIdx.x;
    if (i < E) atomicAdd(&deg32[dst[i] * NBSLOT + (src[i] >> BSH)], 1);
  }
}

template <int K>
__global__ __launch_bounds__(256)
void k_gemm_mfma(const void* __restrict__ Xv, const uint32* __restrict__ PW,
                 const uint32* __restrict__ BFA, uint32* __restrict__ Hh,
                 float* __restrict__ ssrc, float* __restrict__ sdst, int n) {
  gemm_body<K, true>(blockIdx.x, Xv, PW, BFA, Hh, ssrc, sdst, n);
}

// ---------------- per-dst-node softmax aggregation ----------------
// One wave per dst node; segments are bucket-ordered by src (L2 locality).
// BN+bias folded into per-word (A,B) from BNAB.
__global__ __launch_bounds__(256)
void k_agg(const uint32* __restrict__ Hh, const float* __restrict__ ssrc,
           const float* __restrict__ sdst, const int2* __restrict__ offs2,
           const int* __restrict__ csr, const float4* __restrict__ BNAB,
           uint32* __restrict__ Ybf, int n) {
  const int wid = (blockIdx.x * blockDim.x + threadIdx.x) >> 6;
  const int lane = threadIdx.x & 63;
  if (wid >= n) return;
  const int2 se = offs2[wid];
  const float sdv = sdst[wid];
  float acc0 = 0.f, acc1 = 0.f, denom = 0.f;
  for (int base = se.x; base < se.y; base += 64) {
    const int m = min(64, se.y - base);
    int sidx = 0;
    float p = 0.f;
    if (lane < m) {
      sidx = csr[base + lane];
      const float tt = ssrc[sidx] + sdv;
      const float e = (tt > 0.f) ? tt : NEG * tt;
      p = __expf(e);
    }
    denom += wave_sum_f(p);
    const uint32 pu = __float_as_uint(p);
    for (int jj = 0; jj < m; jj += 16) {
      uint32 g[16];
#pragma unroll
      for (int u = 0; u < 16; ++u) {
        if (jj + u < m) {
          const int s = __builtin_amdgcn_readlane(sidx, jj + u);
          g[u] = Hh[(long)s * 64 + lane];
        }
      }
#pragma unroll
      for (int u = 0; u < 16; ++u) {
        if (jj + u < m) {
          const float w = __uint_as_float(__builtin_amdgcn_readlane(pu, jj + u));
          acc0 = fmaf(w, __uint_as_float(g[u] << 16), acc0);
          acc1 = fmaf(w, __uint_as_float(g[u] & 0xffff0000u), acc1);
        }
      }
    }
  }
  const float inv = 1.f / denom;
  const float4 ab = BNAB[lane];
  const float v0 = fmaxf(fmaf(acc0 * inv, ab.x, ab.y), 0.f);
  const float v1 = fmaxf(fmaf(acc1 * inv, ab.z, ab.w), 0.f);
  Ybf[(long)wid * 64 + lane] = f2bf(v0) | (f2bf(v1) << 16);
}

// ---------------- global mean pool + MLP head (bf16 Y, slot layout) ----------------
__global__ __launch_bounds__(256)
void k_pool_head(const uint32* __restrict__ Ybf, const int* __restrict__ batch, int n,
                 const float* __restrict__ lw1, const float* __restrict__ lb1,
                 const float* __restrict__ lw2, const float* __restrict__ lb2,
                 float* __restrict__ out) {
  const int g = blockIdx.x;
  const int wave = threadIdx.x >> 6, lane = threadIdx.x & 63;
  int lo = 0, hi = n;
  while (lo < hi) { int mid = (lo + hi) >> 1; if (batch[mid] < g) lo = mid + 1; else hi = mid; }
  const int start = lo;
  hi = n;
  while (lo < hi) { int mid = (lo + hi) >> 1; if (batch[mid] < g + 1) lo = mid + 1; else hi = mid; }
  const int end = lo;
  const int c0 = (lane >> 4) * 32 + (lane & 15);
  const int c1 = c0 + 16;
  float m0 = 0.f, m1 = 0.f;
  for (int i = start + wave; i < end; i += 4) {
    const uint32 gv = Ybf[(long)i * 64 + lane];
    m0 += __uint_as_float(gv << 16);
    m1 += __uint_as_float(gv & 0xffff0000u);
  }
  __shared__ float red[4][HD];
  red[wave][c0] = m0;
  red[wave][c1] = m1;
  __syncthreads();
  if (wave == 0) {
    m0 = red[0][c0] + red[1][c0] + red[2][c0] + red[3][c0];
    m1 = red[0][c1] + red[1][c1] + red[2][c1] + red[3][c1];
    const float cnt = (float)(end - start);
    const float invc = (cnt > 0.f) ? 1.f / cnt : 0.f;
    m0 *= invc;
    m1 *= invc;
    float t0 = lb1[c0], t1 = lb1[c1];
    for (int k = 0; k < HD; ++k) {
      const int srcl = ((k >> 5) << 4) + (k & 15);
      const float pv = __shfl(((k >> 4) & 1) ? m1 : m0, srcl, 64);
      t0 = fmaf(pv, lw1[k * HD + c0], t0);
      t1 = fmaf(pv, lw1[k * HD + c1], t1);
    }
    t0 = fmaxf(t0, 0.f);
    t1 = fmaxf(t1, 0.f);
    float p = t0 * lw2[c0] + t1 * lw2[c1];
#pragma unroll
    for (int off = 32; off; off >>= 1) p += __shfl_xor(p, off, 64);
    if (lane == 0) out[g] = p + lb2[0];
  }
}

// ---------------- launch ----------------

extern "C" void kernel_launch(void* const* d_in, const int* in_sizes, int n_in,
                              void* d_out, int out_size, void* d_ws, size_t ws_size,
                              hipStream_t stream) {
  const float* x = (const float*)d_in[0];
  const int* ei = (const int*)d_in[1];
  const int* batch = (const int*)d_in[2];
  const float* W1 = (const float*)d_in[3];
  const float* as1 = (const float*)d_in[4];
  const float* ad1 = (const float*)d_in[5];
  const float* b1 = (const float*)d_in[6];
  const float* W2 = (const float*)d_in[7];
  const float* as2 = (const float*)d_in[8];
  const float* ad2 = (const float*)d_in[9];
  const float* b2 = (const float*)d_in[10];
  const float* W3 = (const float*)d_in[11];
  const float* as3 = (const float*)d_in[12];
  const float* ad3 = (const float*)d_in[13];
  const float* b3 = (const float*)d_in[14];
  const float* g1 = (const float*)d_in[15];
  const float* be1 = (const float*)d_in[16];
  const float* m1 = (const float*)d_in[17];
  const float* v1 = (const float*)d_in[18];
  const float* g2 = (const float*)d_in[19];
  const float* be2 = (const float*)d_in[20];
  const float* m2 = (const float*)d_in[21];
  const float* v2 = (const float*)d_in[22];
  const float* g3 = (const float*)d_in[23];
  const float* be3 = (const float*)d_in[24];
  const float* m3 = (const float*)d_in[25];
  const float* v3 = (const float*)d_in[26];
  const float* lw1 = (const float*)d_in[27];
  const float* lb1 = (const float*)d_in[28];
  const float* lw2 = (const float*)d_in[29];
  const float* lb2 = (const float*)d_in[30];

  const int n = in_sizes[0] / 64;  // 50000
  const int E = in_sizes[1] / 2;   // 640000
  const int* src = ei;
  const int* dst = ei + E;

  // workspace carve (4B units)
  uint32* hbuf = (uint32*)d_ws;        // n*64 (bf16x2 packed h)
  uint32* ybuf = hbuf + (long)n * 64;  // n*64 (bf16x2 packed y)
  float* ssrc = (float*)(ybuf + (long)n * 64);  // n
  float* sdstv = ssrc + n;             // n
  int* deg32 = (int*)(sdstv + n);      // n*32
  int2* offs2 = (int2*)(deg32 + (long)n * NBSLOT);  // n int2
  int* cursor = (int*)(offs2 + n);     // n*32
  int* csr = cursor + (long)n * NBSLOT;  // E+n
  int* gcnt = csr + (E + n);           // 1 (+pad)
  uint32* PW1 = (uint32*)(gcnt + 4);   // 4096
  uint32* PW2 = PW1 + 4096;            // 8192
  uint32* PW3 = PW2 + 8192;            // 8192
  uint32* BFA1 = PW3 + 8192;           // 512
  uint32* BFA2 = BFA1 + 512;           // 1024
  uint32* BFA3 = BFA2 + 1024;          // 1024
  float4* BNAB = (float4*)(BFA3 + 1024);  // 3*64 float4

  const int B = 256;
  dim3 blk(B);
  const int nb = (n + B - 1) / B;        // 196
  const int eb = (E + B - 1) / B;        // 2500
  const int zb = ((n * NBSLOT) + B - 1) / B;  // zero blocks for deg32
  const int GB = (n + 63) / 64;          // 782 gemm blocks

  // 1: pack (PW + score fragments + BN fold) + zero deg32/gcnt
  k_pack<<<dim3(83 + zb), blk, 0, stream>>>(
      W1, as1, ad1, W2, as2, ad2, W3, as3, ad3,
      b1, g1, be1, m1, v1, b2, g2, be2, m2, v2, b3, g3, be3, m3, v3,
      PW1, PW2, PW3, BFA1, BFA2, BFA3, BNAB, deg32, gcnt, n);
  // 2: layer-1 gemm (fp32 in) || bucketed edge histogram
  k_gemm1_hist<<<dim3(GB + eb), blk, 0, stream>>>(x, PW1, BFA1, hbuf, ssrc, sdstv, n,
                                                  src, dst, deg32, E, GB);
  // 3: CSR segment allocation (bucketed, scan-free)
  k_alloc<<<dim3(nb), blk, 0, stream>>>((const int4*)deg32, gcnt, offs2, csr,
                                        (int4*)cursor, n);
  // 4: CSR edge fill (bucket-ordered within each node segment)
  k_fill_edges<<<dim3(eb), blk, 0, stream>>>(src, dst, cursor, csr, E);

  const dim3 agrid((n + 3) / 4);
  // 5: agg layer 1
  k_agg<<<agrid, blk, 0, stream>>>(hbuf, ssrc, sdstv, offs2, csr, BNAB + 0, ybuf, n);
  // 6-7: layer 2
  k_gemm_mfma<128><<<dim3(GB), blk, 0, stream>>>(ybuf, PW2, BFA2, hbuf, ssrc, sdstv, n);
  k_agg<<<agrid, blk, 0, stream>>>(hbuf, ssrc, sdstv, offs2, csr, BNAB + 64, ybuf, n);
  // 8-9: layer 3
  k_gemm_mfma<128><<<dim3(GB), blk, 0, stream>>>(ybuf, PW3, BFA3, hbuf, ssrc, sdstv, n);
  k_agg<<<agrid, blk, 0, stream>>>(hbuf, ssrc, sdstv, offs2, csr, BNAB + 128, ybuf, n);
  // 10: pool + head
  k_pool_head<<<dim3(256), blk, 0, stream>>>(ybuf, batch, n, lw1, lb1, lw2, lb2,
                                             (float*)d_out);
}